// Round 19
// baseline (366.688 us; speedup 1.0000x reference)
//
#include <hip/hip_runtime.h>
#include <hip/hip_bf16.h>
#include <math.h>

#define N_NODES 5000
#define N_ELEMS 10
#define C_DIM   128
#define N_EDGE  100000
#define N_BES   8
#define RAD_H   64
#define NL      4
#define SH_DIM  16
#define ONODES  4
#define TPW_ROWS 64

// scales
#define SC_SCALE 0.02795084971874737f    // 1/sqrt(128*10)
#define X_SCALE  0.08838834764831845f    // 1/sqrt(128)
#define R1_SCALE 0.3535533905932738f     // 1/sqrt(8)
#define R_SCALE  0.125f                  // 1/sqrt(64)
#define OUT_SCALE 0.004419417382415922f  // (1/sqrt(128))/20

typedef __attribute__((ext_vector_type(8))) short short8;
typedef __attribute__((ext_vector_type(4))) float f32x4;

__device__ __forceinline__ float silu(float v) { return v / (1.f + __expf(-v)); }
__device__ __forceinline__ unsigned short bf16bits(float v) {
    __hip_bfloat16 h = __float2bfloat16(v);
    return *(unsigned short*)&h;
}

// ---------------- node kernel: sc + x ----------------
__global__ __launch_bounds__(128) void node_kernel(
    const float* __restrict__ node_attrs, const float* __restrict__ node_feats,
    const float* __restrict__ w_skip, const float* __restrict__ w_up,
    float* __restrict__ x, float* __restrict__ sc_out)
{
    int n = blockIdx.x, t = threadIdx.x;
    __shared__ float f[C_DIM];
    __shared__ float at[N_ELEMS];
    f[t] = node_feats[(size_t)n * C_DIM + t];
    if (t < N_ELEMS) at[t] = node_attrs[(size_t)n * N_ELEMS + t];
    __syncthreads();

    float acc = 0.f;
    for (int a = 0; a < N_ELEMS; ++a) {
        float av = at[a];
        if (av != 0.f) {
            const float* wp = w_skip + a * C_DIM + t;
            float s2 = 0.f;
            #pragma unroll 8
            for (int c = 0; c < C_DIM; ++c) s2 += f[c] * wp[(size_t)c * (N_ELEMS * C_DIM)];
            acc += av * s2;
        }
    }
    sc_out[(size_t)n * C_DIM + t] = acc * SC_SCALE;

    float xa = 0.f;
    #pragma unroll 8
    for (int k = 0; k < C_DIM; ++k) xa += f[k] * w_up[k * C_DIM + t];
    x[(size_t)n * C_DIM + t] = xa * X_SCALE;
}

// ---------------- radial MLP v2: one wave per edge, NO loop barriers ----------------
// Round-18 lesson: 3 syncthreads per 4 edges (~75k barriers) serialized the
// block. h-vectors are wave-private -> per-wave LDS + wave_barrier (sched
// fence, zero cost); compiler's lgkmcnt tracking orders same-wave LDS RAW.
__global__ __launch_bounds__(256) void radial_kernel(
    const float* __restrict__ edge_feats,
    const float* __restrict__ w1, const float* __restrict__ w2, const float* __restrict__ w3,
    float* __restrict__ h3out)
{
    __shared__ float w1s[N_BES * RAD_H];
    __shared__ float w2s[RAD_H * RAD_H];
    __shared__ float w3s[RAD_H * RAD_H];
    __shared__ float h1s[4][RAD_H];
    __shared__ float h2s[4][RAD_H];
    int t = threadIdx.x;
    for (int i = t; i < N_BES * RAD_H; i += 256) w1s[i] = w1[i];
    for (int i = t; i < RAD_H * RAD_H; i += 256) { w2s[i] = w2[i]; w3s[i] = w3[i]; }
    __syncthreads();                       // weights ready - the ONLY block barrier
    int wid = t >> 6, j = t & 63;
    for (int e = blockIdx.x * 4 + wid; e < N_EDGE; e += gridDim.x * 4) {
        const float4* ef = (const float4*)(edge_feats + (size_t)e * N_BES);
        float4 f0 = ef[0], f1 = ef[1];     // e wave-uniform -> broadcast loads
        float a = f0.x * w1s[0 * RAD_H + j] + f0.y * w1s[1 * RAD_H + j]
                + f0.z * w1s[2 * RAD_H + j] + f0.w * w1s[3 * RAD_H + j]
                + f1.x * w1s[4 * RAD_H + j] + f1.y * w1s[5 * RAD_H + j]
                + f1.z * w1s[6 * RAD_H + j] + f1.w * w1s[7 * RAD_H + j];
        h1s[wid][j] = silu(a * R1_SCALE);
        __builtin_amdgcn_wave_barrier();   // order write->reads within wave
        {
            const float4* h4 = (const float4*)h1s[wid];
            a = 0.f;
            #pragma unroll
            for (int kk = 0; kk < RAD_H / 4; ++kk) {
                float4 h = h4[kk];
                int k = kk * 4;
                a += h.x * w2s[(k + 0) * RAD_H + j] + h.y * w2s[(k + 1) * RAD_H + j]
                   + h.z * w2s[(k + 2) * RAD_H + j] + h.w * w2s[(k + 3) * RAD_H + j];
            }
        }
        h2s[wid][j] = silu(a * R_SCALE);
        __builtin_amdgcn_wave_barrier();
        {
            const float4* h4 = (const float4*)h2s[wid];
            a = 0.f;
            #pragma unroll
            for (int kk = 0; kk < RAD_H / 4; ++kk) {
                float4 h = h4[kk];
                int k = kk * 4;
                a += h.x * w3s[(k + 0) * RAD_H + j] + h.y * w3s[(k + 1) * RAD_H + j]
                   + h.z * w3s[(k + 2) * RAD_H + j] + h.w * w3s[(k + 3) * RAD_H + j];
            }
        }
        h3out[(size_t)e * RAD_H + j] = silu(a * R_SCALE);
        __builtin_amdgcn_wave_barrier();   // WAR fence before next iter's h1 write
    }
}

// ---------------- CSR build ----------------
__global__ void hist_kernel(const int* __restrict__ recv, int* __restrict__ deg)
{
    int e = blockIdx.x * 256 + threadIdx.x;
    if (e < N_EDGE) atomicAdd(&deg[recv[e]], 1);
}

__global__ __launch_bounds__(256) void scan_kernel(const int* __restrict__ deg, int* __restrict__ offs)
{
    __shared__ int sums[256];
    int t = threadIdx.x;
    int base = t * 20;
    int loc[20]; int s = 0;
    #pragma unroll
    for (int i = 0; i < 20; ++i) { int idx = base + i; int v = (idx < N_NODES) ? deg[idx] : 0; loc[i] = s; s += v; }
    sums[t] = s; __syncthreads();
    for (int off = 1; off < 256; off <<= 1) {
        int v = (t >= off) ? sums[t - off] : 0;
        __syncthreads();
        sums[t] += v;
        __syncthreads();
    }
    int ex = (t == 0) ? 0 : sums[t - 1];
    #pragma unroll
    for (int i = 0; i < 20; ++i) { int idx = base + i; if (idx < N_NODES) offs[idx] = ex + loc[i]; }
    if (t == 255) offs[N_NODES] = sums[255];
}

__global__ void scatter_kernel(const int* __restrict__ recv, const int* __restrict__ offs,
                               int* __restrict__ cursor, int* __restrict__ perm)
{
    int e = blockIdx.x * 256 + threadIdx.x;
    if (e < N_EDGE) {
        int r = recv[e];
        int pos = atomicAdd(&cursor[r], 1);
        perm[offs[r] + pos] = e;
    }
}

// ---------------- reorder: sid_arr[idx]=sender[perm[idx]], ea_perm[idx]=edge_attrs[perm[idx]] ----------------
__global__ void reorder_kernel(const int* __restrict__ perm, const int* __restrict__ sender,
                               const float* __restrict__ edge_attrs,
                               int* __restrict__ sid_arr, float4* __restrict__ ea_perm4)
{
    int idx = blockIdx.x * 256 + threadIdx.x;
    if (idx < N_EDGE) {
        int e = perm[idx];
        sid_arr[idx] = sender[e];
        const float4* src = (const float4*)(edge_attrs + (size_t)e * SH_DIM);
        float4* dst = ea_perm4 + (size_t)idx * 4;
        dst[0] = src[0]; dst[1] = src[1]; dst[2] = src[2]; dst[3] = src[3];
    }
}

// ---------------- tpw GEMM via MFMA (bf16): tpw[i,:] = h3[perm[i],:] @ w4*R_SCALE ----------------
__global__ __launch_bounds__(256, 2) void tpw_gemm_kernel(
    const int* __restrict__ perm, const float* __restrict__ h3,
    const float* __restrict__ w4, __hip_bfloat16* __restrict__ tpw)
{
    __shared__ unsigned short As[64 * 72];    // [row][k] pad+8  (9.2 KB)
    __shared__ unsigned short Bp[128 * 72];   // [n][k]  pad+8  (18.4 KB)
    __shared__ unsigned short epi[64 * 136];  // [row][n] pad+8 (17.4 KB)
    int l = blockIdx.y, t = threadIdx.x;
    int lane = t & 63, wid = t >> 6;

    for (int idx = t; idx < RAD_H * C_DIM; idx += 256) {
        int k = idx >> 7, n = idx & 127;
        Bp[n * 72 + k] = bf16bits(w4[k * (NL * C_DIM) + l * C_DIM + n] * R_SCALE);
    }
    __syncthreads();

    short8 bfr[2][8];
    #pragma unroll
    for (int s = 0; s < 2; ++s)
        #pragma unroll
        for (int f = 0; f < 8; ++f)
            bfr[s][f] = *(const short8*)&Bp[(f * 16 + (lane & 15)) * 72 + s * 32 + (lane >> 4) * 8];

    const int ntiles = (N_EDGE + TPW_ROWS - 1) / TPW_ROWS;   // 1563
    for (int tile = blockIdx.x; tile < ntiles; tile += gridDim.x) {
        int i0 = tile * TPW_ROWS;
        {
            int r = t >> 2, q = t & 3;
            int e = perm[min(i0 + r, N_EDGE - 1)];
            const float4* src = (const float4*)(h3 + (size_t)e * RAD_H + q * 16);
            unsigned short tmp[16];
            #pragma unroll
            for (int v = 0; v < 4; ++v) {
                float4 fv = src[v];
                tmp[v * 4 + 0] = bf16bits(fv.x);
                tmp[v * 4 + 1] = bf16bits(fv.y);
                tmp[v * 4 + 2] = bf16bits(fv.z);
                tmp[v * 4 + 3] = bf16bits(fv.w);
            }
            *(short8*)&As[r * 72 + q * 16]     = *(short8*)&tmp[0];
            *(short8*)&As[r * 72 + q * 16 + 8] = *(short8*)&tmp[8];
        }
        __syncthreads();    // As ready; prev copy-out done

        f32x4 acc[8] = {};
        #pragma unroll
        for (int s = 0; s < 2; ++s) {
            short8 a = *(const short8*)&As[(wid * 16 + (lane & 15)) * 72 + s * 32 + (lane >> 4) * 8];
            #pragma unroll
            for (int f = 0; f < 8; ++f)
                acc[f] = __builtin_amdgcn_mfma_f32_16x16x32_bf16(a, bfr[s][f], acc[f], 0, 0, 0);
        }
        #pragma unroll
        for (int f = 0; f < 8; ++f)
            #pragma unroll
            for (int r = 0; r < 4; ++r)
                epi[(wid * 16 + (lane >> 4) * 4 + r) * 136 + f * 16 + (lane & 15)] = bf16bits(acc[f][r]);
        __syncthreads();    // epi ready; all As reads done

        {
            int row = t >> 2, q = t & 3;
            if (i0 + row < N_EDGE) {
                unsigned short* dst = (unsigned short*)tpw + (size_t)(i0 + row) * (NL * C_DIM) + l * C_DIM + q * 32;
                #pragma unroll
                for (int v = 0; v < 4; ++v)
                    *(short8*)(dst + v * 8) = *(const short8*)&epi[row * 136 + q * 32 + v * 8];
            }
        }
    }
}

// ---------------- stream gather v3: 256 thr (l=t>>6 wave-uniform, 2 c's/thread) ----------------
__global__ __launch_bounds__(256, 4) void stream_gather_kernel(
    const int* __restrict__ offs, const int* __restrict__ sid_arr,
    const float* __restrict__ x, const float* __restrict__ ea_perm,
    const __hip_bfloat16* __restrict__ tpw, float* __restrict__ msg)
{
    int n = blockIdx.x, t = threadIdx.x;
    int cq = t & 63, l = t >> 6;          // l wave-uniform; c = cq*2, cq*2+1
    int c0 = cq * 2;
    float acc[7][2] = {};
    int nm = 2 * l + 1;
    int start = offs[n], end = offs[n + 1];

    for (int base = start; base < end; base += 4) {
        int idxb[4], sidb[4];
        #pragma unroll
        for (int j = 0; j < 4; ++j) idxb[j] = min(base + j, end - 1);
        #pragma unroll
        for (int j = 0; j < 4; ++j) sidb[j] = sid_arr[idxb[j]];   // wave-uniform -> s_load

        unsigned int tpb[4];
        float2 xv[4];
        #pragma unroll
        for (int j = 0; j < 4; ++j)
            tpb[j] = *(const unsigned int*)((const unsigned short*)tpw + (size_t)idxb[j] * (NL * C_DIM) + l * C_DIM + c0);
        #pragma unroll
        for (int j = 0; j < 4; ++j)
            xv[j] = *(const float2*)(x + (size_t)sidb[j] * C_DIM + c0);
        asm volatile("" : "+v"(tpb[0]), "+v"(tpb[1]), "+v"(tpb[2]), "+v"(tpb[3]),
                          "+v"(xv[0].x), "+v"(xv[0].y), "+v"(xv[1].x), "+v"(xv[1].y),
                          "+v"(xv[2].x), "+v"(xv[2].y), "+v"(xv[3].x), "+v"(xv[3].y));

        #pragma unroll
        for (int j = 0; j < 4; ++j) {
            unsigned int lo = (tpb[j] & 0xFFFFu) << 16;
            unsigned int hi = tpb[j] & 0xFFFF0000u;
            float tp0 = __uint_as_float(lo);
            float tp1 = __uint_as_float(hi);
            bool valid = (base + j < end);
            float xt0 = valid ? tp0 * xv[j].x : 0.f;
            float xt1 = valid ? tp1 * xv[j].y : 0.f;
            const float* ear = ea_perm + (size_t)idxb[j] * SH_DIM + l * l;   // wave-uniform
            #pragma unroll
            for (int m = 0; m < 7; ++m)
                if (m < nm) { acc[m][0] += ear[m] * xt0; acc[m][1] += ear[m] * xt1; }
        }
    }
    float* mout = msg + (size_t)n * (SH_DIM * C_DIM) + (size_t)(l * l) * C_DIM + c0;
    #pragma unroll
    for (int m = 0; m < 7; ++m)
        if (m < nm) *(float2*)(mout + (size_t)m * C_DIM) = make_float2(acc[m][0], acc[m][1]);
}

// ---------------- fallback fused gather (round-7, e-indexed) ----------------
__global__ __launch_bounds__(512, 4) void fused_gather_kernel(
    const int* __restrict__ perm, const int* __restrict__ offs,
    const int* __restrict__ sender, const float* __restrict__ x,
    const float* __restrict__ edge_attrs, const float* __restrict__ h3,
    const float* __restrict__ w4, float* __restrict__ msg)
{
    int n = blockIdx.x, t = threadIdx.x;
    int c = t & 127, l = t >> 7;
    float wc[RAD_H];
    #pragma unroll
    for (int k = 0; k < RAD_H; ++k)
        wc[k] = w4[k * (NL * C_DIM) + l * C_DIM + c];

    float acc[7] = {0.f, 0.f, 0.f, 0.f, 0.f, 0.f, 0.f};
    int nm = 2 * l + 1;
    int start = offs[n], end = offs[n + 1];
    if (start < end) {
        int e = __builtin_amdgcn_readfirstlane(perm[start]);
        int s = __builtin_amdgcn_readfirstlane(sender[e]);
        for (int idx = start; idx < end; ++idx) {
            #pragma unroll
            for (int k = 0; k < RAD_H; k += 8)
                asm volatile("" : "+v"(wc[k]), "+v"(wc[k+1]), "+v"(wc[k+2]), "+v"(wc[k+3]),
                                  "+v"(wc[k+4]), "+v"(wc[k+5]), "+v"(wc[k+6]), "+v"(wc[k+7]));
            int e_cur = e, s_cur = s;
            if (idx + 1 < end) {
                e = __builtin_amdgcn_readfirstlane(perm[idx + 1]);
                s = __builtin_amdgcn_readfirstlane(sender[e]);
            }
            const float* h3r = h3 + (size_t)e_cur * RAD_H;
            float xv = x[(size_t)s_cur * C_DIM + c];
            float tp0 = 0.f, tp1 = 0.f, tp2 = 0.f, tp3 = 0.f;
            #pragma unroll
            for (int q = 0; q < RAD_H / 4; ++q) {
                tp0 += h3r[4 * q + 0] * wc[4 * q + 0];
                tp1 += h3r[4 * q + 1] * wc[4 * q + 1];
                tp2 += h3r[4 * q + 2] * wc[4 * q + 2];
                tp3 += h3r[4 * q + 3] * wc[4 * q + 3];
            }
            float tp = (tp0 + tp1) + (tp2 + tp3);
            float xt = xv * (tp * R_SCALE);
            const float* ear = edge_attrs + (size_t)e_cur * SH_DIM + l * l;
            #pragma unroll
            for (int j = 0; j < 7; ++j)
                if (j < nm) acc[j] += ear[j] * xt;
        }
    }
    float* mout = msg + (size_t)n * (SH_DIM * C_DIM) + (size_t)(l * l) * C_DIM + c;
    #pragma unroll
    for (int j = 0; j < 7; ++j)
        if (j < nm) mout[(size_t)j * C_DIM] = acc[j];
}

// ---------------- out[n,m,d] = sum_c msg[n,m,c]*w_out[l(m),c,d]  (in place on d_out) ----------------
// v3: ONODES 8->4 (grid 625->1250). Round-18 lesson: 625 blocks = 2.4/CU ->
// occupancy-starved (26%). Same 32KB LDS.
__global__ __launch_bounds__(256, 4) void out_kernel(
    float* __restrict__ out, const float* __restrict__ w_out)
{
    __shared__ float wlds[64 * C_DIM];        // 32 KB half-k panel
    int nb = blockIdx.x * ONODES, t = threadIdx.x;
    int dq = t & 31, rg = t >> 5;
    int d0 = dq * 4;
    #pragma unroll
    for (int l = 0; l < 4; ++l) {
        const int ms = l * l, cnt = 2 * l + 1;
        const int ntiles = ONODES * cnt / 4;  // 1,3,5,7
        float acc[2][4][4] = {};
        #pragma unroll
        for (int half = 0; half < 2; ++half) {
            const int k0h = half * 64;
            __syncthreads();
            {
                const float4* src = (const float4*)(w_out + ((size_t)l * C_DIM + k0h) * C_DIM);
                float4* dst = (float4*)wlds;
                for (int i = t; i < 64 * C_DIM / 4; i += 256) dst[i] = src[i];
            }
            __syncthreads();
            #pragma unroll
            for (int slot = 0; slot < 2; ++slot) {
                int ti = rg + slot * 8;
                if (ti < ntiles) {
                    int r0 = ti * 4;
                    const float* mrow[4];
                    #pragma unroll
                    for (int i = 0; i < 4; ++i) {
                        int r = r0 + i;
                        int node = r / cnt, mm = ms + r % cnt;
                        mrow[i] = out + ((size_t)(nb + node) * SH_DIM + mm) * C_DIM + k0h;
                    }
                    #pragma unroll 2
                    for (int k0 = 0; k0 < 64; k0 += 4) {
                        float4 b0 = *(const float4*)&wlds[(k0 + 0) * C_DIM + d0];
                        float4 b1 = *(const float4*)&wlds[(k0 + 1) * C_DIM + d0];
                        float4 b2 = *(const float4*)&wlds[(k0 + 2) * C_DIM + d0];
                        float4 b3 = *(const float4*)&wlds[(k0 + 3) * C_DIM + d0];
                        #pragma unroll
                        for (int i = 0; i < 4; ++i) {
                            float4 a = *(const float4*)(mrow[i] + k0);
                            acc[slot][i][0] += a.x * b0.x + a.y * b1.x + a.z * b2.x + a.w * b3.x;
                            acc[slot][i][1] += a.x * b0.y + a.y * b1.y + a.z * b2.y + a.w * b3.y;
                            acc[slot][i][2] += a.x * b0.z + a.y * b1.z + a.z * b2.z + a.w * b3.z;
                            acc[slot][i][3] += a.x * b0.w + a.y * b1.w + a.z * b2.w + a.w * b3.w;
                        }
                    }
                }
            }
        }
        #pragma unroll
        for (int slot = 0; slot < 2; ++slot) {
            int ti = rg + slot * 8;
            if (ti < ntiles) {
                int r0 = ti * 4;
                #pragma unroll
                for (int i = 0; i < 4; ++i) {
                    int r = r0 + i;
                    int node = r / cnt, mm = ms + r % cnt;
                    float4 r4 = make_float4(acc[slot][i][0] * OUT_SCALE, acc[slot][i][1] * OUT_SCALE,
                                            acc[slot][i][2] * OUT_SCALE, acc[slot][i][3] * OUT_SCALE);
                    *(float4*)(out + ((size_t)(nb + node) * SH_DIM + mm) * C_DIM + d0) = r4;
                }
            }
        }
    }
}

extern "C" void kernel_launch(void* const* d_in, const int* in_sizes, int n_in,
                              void* d_out, int out_size, void* d_ws, size_t ws_size,
                              hipStream_t stream)
{
    const float* node_attrs = (const float*)d_in[0];
    const float* node_feats = (const float*)d_in[1];
    const float* edge_attrs = (const float*)d_in[2];
    const float* edge_feats = (const float*)d_in[3];
    const int*   edge_index = (const int*)d_in[4];
    const float* w_up   = (const float*)d_in[5];
    const float* w_rad1 = (const float*)d_in[6];
    const float* w_rad2 = (const float*)d_in[7];
    const float* w_rad3 = (const float*)d_in[8];
    const float* w_rad4 = (const float*)d_in[9];
    const float* w_skip = (const float*)d_in[10];
    const float* w_out  = (const float*)d_in[11];
    const int* sender = edge_index;
    const int* recv   = edge_index + N_EDGE;

    float* out = (float*)d_out;                                 // msg staged here, then in-place
    float* sc  = out + (size_t)N_NODES * SH_DIM * C_DIM;

    // workspace layout (ws >= 233.4 MB proven; this needs ~138 MB)
    float* x   = (float*)d_ws;
    float* h3  = x + (size_t)N_NODES * C_DIM;
    int* deg    = (int*)(h3 + (size_t)N_EDGE * RAD_H);
    int* cursor = deg + 5120;
    int* offs   = cursor + 5120;
    int* perm   = offs + 5124;
    __hip_bfloat16* tpw = (__hip_bfloat16*)(perm + N_EDGE);
    int* sid_arr = (int*)(tpw + (size_t)N_EDGE * NL * C_DIM);
    float* ea_perm = (float*)(sid_arr + N_EDGE);
    size_t need = (size_t)((char*)(ea_perm + (size_t)N_EDGE * SH_DIM) - (char*)d_ws);
    int mode = (ws_size >= need) ? 1 : 0;

    hipMemsetAsync(deg, 0, 2 * 5120 * sizeof(int), stream);

    node_kernel<<<N_NODES, 128, 0, stream>>>(node_attrs, node_feats, w_skip, w_up, x, sc);
    radial_kernel<<<1024, 256, 0, stream>>>(edge_feats, w_rad1, w_rad2, w_rad3, h3);

    hist_kernel<<<(N_EDGE + 255) / 256, 256, 0, stream>>>(recv, deg);
    scan_kernel<<<1, 256, 0, stream>>>(deg, offs);
    scatter_kernel<<<(N_EDGE + 255) / 256, 256, 0, stream>>>(recv, offs, cursor, perm);

    if (mode == 1) {
        reorder_kernel<<<(N_EDGE + 255) / 256, 256, 0, stream>>>(perm, sender, edge_attrs, sid_arr, (float4*)ea_perm);
        tpw_gemm_kernel<<<dim3(391, 4), 256, 0, stream>>>(perm, h3, w_rad4, tpw);
        stream_gather_kernel<<<N_NODES, 256, 0, stream>>>(offs, sid_arr, x, ea_perm, tpw, out);
    } else {
        fused_gather_kernel<<<N_NODES, 512, 0, stream>>>(perm, offs, sender, x, edge_attrs, h3, w_rad4, out);
    }

    out_kernel<<<N_NODES / ONODES, 256, 0, stream>>>(out, w_out);
}

// Round 20
// 301.098 us; speedup vs baseline: 1.2178x; 1.2178x over previous
//
#include <hip/hip_runtime.h>
#include <hip/hip_bf16.h>
#include <math.h>

#define N_NODES 5000
#define N_ELEMS 10
#define C_DIM   128
#define N_EDGE  100000
#define N_BES   8
#define RAD_H   64
#define NL      4
#define SH_DIM  16
#define TPW_ROWS 64

// scales
#define SC_SCALE 0.02795084971874737f    // 1/sqrt(128*10)
#define X_SCALE  0.08838834764831845f    // 1/sqrt(128)
#define R1_SCALE 0.3535533905932738f     // 1/sqrt(8)
#define R_SCALE  0.125f                  // 1/sqrt(64)
#define OUT_SCALE 0.004419417382415922f  // (1/sqrt(128))/20

typedef __attribute__((ext_vector_type(8))) short short8;
typedef __attribute__((ext_vector_type(4))) float f32x4;

__device__ __forceinline__ float silu(float v) { return v / (1.f + __expf(-v)); }
__device__ __forceinline__ unsigned short bf16bits(float v) {
    __hip_bfloat16 h = __float2bfloat16(v);
    return *(unsigned short*)&h;
}

// ---------------- node kernel: sc + x ----------------
__global__ __launch_bounds__(128) void node_kernel(
    const float* __restrict__ node_attrs, const float* __restrict__ node_feats,
    const float* __restrict__ w_skip, const float* __restrict__ w_up,
    float* __restrict__ x, float* __restrict__ sc_out)
{
    int n = blockIdx.x, t = threadIdx.x;
    __shared__ float f[C_DIM];
    __shared__ float at[N_ELEMS];
    f[t] = node_feats[(size_t)n * C_DIM + t];
    if (t < N_ELEMS) at[t] = node_attrs[(size_t)n * N_ELEMS + t];
    __syncthreads();

    float acc = 0.f;
    for (int a = 0; a < N_ELEMS; ++a) {
        float av = at[a];
        if (av != 0.f) {
            const float* wp = w_skip + a * C_DIM + t;
            float s2 = 0.f;
            #pragma unroll 8
            for (int c = 0; c < C_DIM; ++c) s2 += f[c] * wp[(size_t)c * (N_ELEMS * C_DIM)];
            acc += av * s2;
        }
    }
    sc_out[(size_t)n * C_DIM + t] = acc * SC_SCALE;

    float xa = 0.f;
    #pragma unroll 8
    for (int k = 0; k < C_DIM; ++k) xa += f[k] * w_up[k * C_DIM + t];
    x[(size_t)n * C_DIM + t] = xa * X_SCALE;
}

// ---------------- radial MLP v2: one wave per edge, NO loop barriers ----------------
__global__ __launch_bounds__(256) void radial_kernel(
    const float* __restrict__ edge_feats,
    const float* __restrict__ w1, const float* __restrict__ w2, const float* __restrict__ w3,
    float* __restrict__ h3out)
{
    __shared__ float w1s[N_BES * RAD_H];
    __shared__ float w2s[RAD_H * RAD_H];
    __shared__ float w3s[RAD_H * RAD_H];
    __shared__ float h1s[4][RAD_H];
    __shared__ float h2s[4][RAD_H];
    int t = threadIdx.x;
    for (int i = t; i < N_BES * RAD_H; i += 256) w1s[i] = w1[i];
    for (int i = t; i < RAD_H * RAD_H; i += 256) { w2s[i] = w2[i]; w3s[i] = w3[i]; }
    __syncthreads();                       // weights ready - the ONLY block barrier
    int wid = t >> 6, j = t & 63;
    for (int e = blockIdx.x * 4 + wid; e < N_EDGE; e += gridDim.x * 4) {
        const float4* ef = (const float4*)(edge_feats + (size_t)e * N_BES);
        float4 f0 = ef[0], f1 = ef[1];
        float a = f0.x * w1s[0 * RAD_H + j] + f0.y * w1s[1 * RAD_H + j]
                + f0.z * w1s[2 * RAD_H + j] + f0.w * w1s[3 * RAD_H + j]
                + f1.x * w1s[4 * RAD_H + j] + f1.y * w1s[5 * RAD_H + j]
                + f1.z * w1s[6 * RAD_H + j] + f1.w * w1s[7 * RAD_H + j];
        h1s[wid][j] = silu(a * R1_SCALE);
        __builtin_amdgcn_wave_barrier();
        {
            const float4* h4 = (const float4*)h1s[wid];
            a = 0.f;
            #pragma unroll
            for (int kk = 0; kk < RAD_H / 4; ++kk) {
                float4 h = h4[kk];
                int k = kk * 4;
                a += h.x * w2s[(k + 0) * RAD_H + j] + h.y * w2s[(k + 1) * RAD_H + j]
                   + h.z * w2s[(k + 2) * RAD_H + j] + h.w * w2s[(k + 3) * RAD_H + j];
            }
        }
        h2s[wid][j] = silu(a * R_SCALE);
        __builtin_amdgcn_wave_barrier();
        {
            const float4* h4 = (const float4*)h2s[wid];
            a = 0.f;
            #pragma unroll
            for (int kk = 0; kk < RAD_H / 4; ++kk) {
                float4 h = h4[kk];
                int k = kk * 4;
                a += h.x * w3s[(k + 0) * RAD_H + j] + h.y * w3s[(k + 1) * RAD_H + j]
                   + h.z * w3s[(k + 2) * RAD_H + j] + h.w * w3s[(k + 3) * RAD_H + j];
            }
        }
        h3out[(size_t)e * RAD_H + j] = silu(a * R_SCALE);
        __builtin_amdgcn_wave_barrier();
    }
}

// ---------------- CSR build ----------------
__global__ void hist_kernel(const int* __restrict__ recv, int* __restrict__ deg)
{
    int e = blockIdx.x * 256 + threadIdx.x;
    if (e < N_EDGE) atomicAdd(&deg[recv[e]], 1);
}

__global__ __launch_bounds__(256) void scan_kernel(const int* __restrict__ deg, int* __restrict__ offs)
{
    __shared__ int sums[256];
    int t = threadIdx.x;
    int base = t * 20;
    int loc[20]; int s = 0;
    #pragma unroll
    for (int i = 0; i < 20; ++i) { int idx = base + i; int v = (idx < N_NODES) ? deg[idx] : 0; loc[i] = s; s += v; }
    sums[t] = s; __syncthreads();
    for (int off = 1; off < 256; off <<= 1) {
        int v = (t >= off) ? sums[t - off] : 0;
        __syncthreads();
        sums[t] += v;
        __syncthreads();
    }
    int ex = (t == 0) ? 0 : sums[t - 1];
    #pragma unroll
    for (int i = 0; i < 20; ++i) { int idx = base + i; if (idx < N_NODES) offs[idx] = ex + loc[i]; }
    if (t == 255) offs[N_NODES] = sums[255];
}

__global__ void scatter_kernel(const int* __restrict__ recv, const int* __restrict__ offs,
                               int* __restrict__ cursor, int* __restrict__ perm)
{
    int e = blockIdx.x * 256 + threadIdx.x;
    if (e < N_EDGE) {
        int r = recv[e];
        int pos = atomicAdd(&cursor[r], 1);
        perm[offs[r] + pos] = e;
    }
}

// ---------------- reorder: sid_arr[idx]=sender[perm[idx]], ea_perm[idx]=edge_attrs[perm[idx]] ----------------
__global__ void reorder_kernel(const int* __restrict__ perm, const int* __restrict__ sender,
                               const float* __restrict__ edge_attrs,
                               int* __restrict__ sid_arr, float4* __restrict__ ea_perm4)
{
    int idx = blockIdx.x * 256 + threadIdx.x;
    if (idx < N_EDGE) {
        int e = perm[idx];
        sid_arr[idx] = sender[e];
        const float4* src = (const float4*)(edge_attrs + (size_t)e * SH_DIM);
        float4* dst = ea_perm4 + (size_t)idx * 4;
        dst[0] = src[0]; dst[1] = src[1]; dst[2] = src[2]; dst[3] = src[3];
    }
}

// ---------------- tpw GEMM via MFMA (bf16): tpw[i,:] = h3[perm[i],:] @ w4*R_SCALE ----------------
__global__ __launch_bounds__(256, 2) void tpw_gemm_kernel(
    const int* __restrict__ perm, const float* __restrict__ h3,
    const float* __restrict__ w4, __hip_bfloat16* __restrict__ tpw)
{
    __shared__ unsigned short As[64 * 72];
    __shared__ unsigned short Bp[128 * 72];
    __shared__ unsigned short epi[64 * 136];
    int l = blockIdx.y, t = threadIdx.x;
    int lane = t & 63, wid = t >> 6;

    for (int idx = t; idx < RAD_H * C_DIM; idx += 256) {
        int k = idx >> 7, n = idx & 127;
        Bp[n * 72 + k] = bf16bits(w4[k * (NL * C_DIM) + l * C_DIM + n] * R_SCALE);
    }
    __syncthreads();

    short8 bfr[2][8];
    #pragma unroll
    for (int s = 0; s < 2; ++s)
        #pragma unroll
        for (int f = 0; f < 8; ++f)
            bfr[s][f] = *(const short8*)&Bp[(f * 16 + (lane & 15)) * 72 + s * 32 + (lane >> 4) * 8];

    const int ntiles = (N_EDGE + TPW_ROWS - 1) / TPW_ROWS;
    for (int tile = blockIdx.x; tile < ntiles; tile += gridDim.x) {
        int i0 = tile * TPW_ROWS;
        {
            int r = t >> 2, q = t & 3;
            int e = perm[min(i0 + r, N_EDGE - 1)];
            const float4* src = (const float4*)(h3 + (size_t)e * RAD_H + q * 16);
            unsigned short tmp[16];
            #pragma unroll
            for (int v = 0; v < 4; ++v) {
                float4 fv = src[v];
                tmp[v * 4 + 0] = bf16bits(fv.x);
                tmp[v * 4 + 1] = bf16bits(fv.y);
                tmp[v * 4 + 2] = bf16bits(fv.z);
                tmp[v * 4 + 3] = bf16bits(fv.w);
            }
            *(short8*)&As[r * 72 + q * 16]     = *(short8*)&tmp[0];
            *(short8*)&As[r * 72 + q * 16 + 8] = *(short8*)&tmp[8];
        }
        __syncthreads();

        f32x4 acc[8] = {};
        #pragma unroll
        for (int s = 0; s < 2; ++s) {
            short8 a = *(const short8*)&As[(wid * 16 + (lane & 15)) * 72 + s * 32 + (lane >> 4) * 8];
            #pragma unroll
            for (int f = 0; f < 8; ++f)
                acc[f] = __builtin_amdgcn_mfma_f32_16x16x32_bf16(a, bfr[s][f], acc[f], 0, 0, 0);
        }
        #pragma unroll
        for (int f = 0; f < 8; ++f)
            #pragma unroll
            for (int r = 0; r < 4; ++r)
                epi[(wid * 16 + (lane >> 4) * 4 + r) * 136 + f * 16 + (lane & 15)] = bf16bits(acc[f][r]);
        __syncthreads();

        {
            int row = t >> 2, q = t & 3;
            if (i0 + row < N_EDGE) {
                unsigned short* dst = (unsigned short*)tpw + (size_t)(i0 + row) * (NL * C_DIM) + l * C_DIM + q * 32;
                #pragma unroll
                for (int v = 0; v < 4; ++v)
                    *(short8*)(dst + v * 8) = *(const short8*)&epi[row * 136 + q * 32 + v * 8];
            }
        }
    }
}

// ---------------- stream gather v3: 256 thr (l=t>>6 wave-uniform, 2 c's/thread) ----------------
__global__ __launch_bounds__(256, 4) void stream_gather_kernel(
    const int* __restrict__ offs, const int* __restrict__ sid_arr,
    const float* __restrict__ x, const float* __restrict__ ea_perm,
    const __hip_bfloat16* __restrict__ tpw, float* __restrict__ msg)
{
    int n = blockIdx.x, t = threadIdx.x;
    int cq = t & 63, l = t >> 6;
    int c0 = cq * 2;
    float acc[7][2] = {};
    int nm = 2 * l + 1;
    int start = offs[n], end = offs[n + 1];

    for (int base = start; base < end; base += 4) {
        int idxb[4], sidb[4];
        #pragma unroll
        for (int j = 0; j < 4; ++j) idxb[j] = min(base + j, end - 1);
        #pragma unroll
        for (int j = 0; j < 4; ++j) sidb[j] = sid_arr[idxb[j]];

        unsigned int tpb[4];
        float2 xv[4];
        #pragma unroll
        for (int j = 0; j < 4; ++j)
            tpb[j] = *(const unsigned int*)((const unsigned short*)tpw + (size_t)idxb[j] * (NL * C_DIM) + l * C_DIM + c0);
        #pragma unroll
        for (int j = 0; j < 4; ++j)
            xv[j] = *(const float2*)(x + (size_t)sidb[j] * C_DIM + c0);
        asm volatile("" : "+v"(tpb[0]), "+v"(tpb[1]), "+v"(tpb[2]), "+v"(tpb[3]),
                          "+v"(xv[0].x), "+v"(xv[0].y), "+v"(xv[1].x), "+v"(xv[1].y),
                          "+v"(xv[2].x), "+v"(xv[2].y), "+v"(xv[3].x), "+v"(xv[3].y));

        #pragma unroll
        for (int j = 0; j < 4; ++j) {
            unsigned int lo = (tpb[j] & 0xFFFFu) << 16;
            unsigned int hi = tpb[j] & 0xFFFF0000u;
            float tp0 = __uint_as_float(lo);
            float tp1 = __uint_as_float(hi);
            bool valid = (base + j < end);
            float xt0 = valid ? tp0 * xv[j].x : 0.f;
            float xt1 = valid ? tp1 * xv[j].y : 0.f;
            const float* ear = ea_perm + (size_t)idxb[j] * SH_DIM + l * l;
            #pragma unroll
            for (int m = 0; m < 7; ++m)
                if (m < nm) { acc[m][0] += ear[m] * xt0; acc[m][1] += ear[m] * xt1; }
        }
    }
    float* mout = msg + (size_t)n * (SH_DIM * C_DIM) + (size_t)(l * l) * C_DIM + c0;
    #pragma unroll
    for (int m = 0; m < 7; ++m)
        if (m < nm) *(float2*)(mout + (size_t)m * C_DIM) = make_float2(acc[m][0], acc[m][1]);
}

// ---------------- fallback fused gather (round-7, e-indexed) ----------------
__global__ __launch_bounds__(512, 4) void fused_gather_kernel(
    const int* __restrict__ perm, const int* __restrict__ offs,
    const int* __restrict__ sender, const float* __restrict__ x,
    const float* __restrict__ edge_attrs, const float* __restrict__ h3,
    const float* __restrict__ w4, float* __restrict__ msg)
{
    int n = blockIdx.x, t = threadIdx.x;
    int c = t & 127, l = t >> 7;
    float wc[RAD_H];
    #pragma unroll
    for (int k = 0; k < RAD_H; ++k)
        wc[k] = w4[k * (NL * C_DIM) + l * C_DIM + c];

    float acc[7] = {0.f, 0.f, 0.f, 0.f, 0.f, 0.f, 0.f};
    int nm = 2 * l + 1;
    int start = offs[n], end = offs[n + 1];
    if (start < end) {
        int e = __builtin_amdgcn_readfirstlane(perm[start]);
        int s = __builtin_amdgcn_readfirstlane(sender[e]);
        for (int idx = start; idx < end; ++idx) {
            #pragma unroll
            for (int k = 0; k < RAD_H; k += 8)
                asm volatile("" : "+v"(wc[k]), "+v"(wc[k+1]), "+v"(wc[k+2]), "+v"(wc[k+3]),
                                  "+v"(wc[k+4]), "+v"(wc[k+5]), "+v"(wc[k+6]), "+v"(wc[k+7]));
            int e_cur = e, s_cur = s;
            if (idx + 1 < end) {
                e = __builtin_amdgcn_readfirstlane(perm[idx + 1]);
                s = __builtin_amdgcn_readfirstlane(sender[e]);
            }
            const float* h3r = h3 + (size_t)e_cur * RAD_H;
            float xv = x[(size_t)s_cur * C_DIM + c];
            float tp0 = 0.f, tp1 = 0.f, tp2 = 0.f, tp3 = 0.f;
            #pragma unroll
            for (int q = 0; q < RAD_H / 4; ++q) {
                tp0 += h3r[4 * q + 0] * wc[4 * q + 0];
                tp1 += h3r[4 * q + 1] * wc[4 * q + 1];
                tp2 += h3r[4 * q + 2] * wc[4 * q + 2];
                tp3 += h3r[4 * q + 3] * wc[4 * q + 3];
            }
            float tp = (tp0 + tp1) + (tp2 + tp3);
            float xt = xv * (tp * R_SCALE);
            const float* ear = edge_attrs + (size_t)e_cur * SH_DIM + l * l;
            #pragma unroll
            for (int j = 0; j < 7; ++j)
                if (j < nm) acc[j] += ear[j] * xt;
        }
    }
    float* mout = msg + (size_t)n * (SH_DIM * C_DIM) + (size_t)(l * l) * C_DIM + c;
    #pragma unroll
    for (int j = 0; j < 7; ++j)
        if (j < nm) mout[(size_t)j * C_DIM] = acc[j];
}

// ---------------- out transform via MFMA: per l, [M_l x 128] @ w_out[l] (in place on d_out) ----------------
// Round-19 lesson: VALU out_kernel partition wasted ~50% threads and was
// occupancy/latency-bound at 110-125us with a ~15us traffic floor. GEMM-shaped
// -> matrix cores. A = msg rows (f32->bf16 staged), B = w_out[l]^T bf16 with
// OUT_SCALE folded. In-place safe: each tile reads its own 64 rows to LDS
// before writing them; rows partition disjointly by l.
__global__ __launch_bounds__(256, 2) void out_mfma_kernel(
    float* __restrict__ out, const float* __restrict__ w_out)
{
    __shared__ unsigned short As[64 * 136];    // [row][k] pad+8 (17.4 KB)
    __shared__ unsigned short Bp[128 * 136];   // [n][k]  pad+8 (34.8 KB)
    int l = blockIdx.y, t = threadIdx.x;
    int lane = t & 63, wid = t >> 6;
    const int cnt = 2 * l + 1, ms = l * l;
    const int M = N_NODES * cnt;
    const int ntile = (M + 63) >> 6;
    if (blockIdx.x >= ntile) return;           // uniform early-exit

    // stage B: Bp[n][k] = bf16(w_out[l][k][n] * OUT_SCALE)
    for (int idx = t; idx < C_DIM * C_DIM; idx += 256) {
        int k = idx >> 7, n = idx & 127;
        Bp[n * 136 + k] = bf16bits(w_out[((size_t)l * C_DIM + k) * C_DIM + n] * OUT_SCALE);
    }
    __syncthreads();

    for (int tile = blockIdx.x; tile < ntile; tile += gridDim.x) {
        int i0 = tile << 6;
        // stage A: 64 msg rows f32->bf16 (4 threads/row, 32 k each)
        {
            int r = t >> 2, q = t & 3;
            int g = min(i0 + r, M - 1);
            int node = g / cnt, mm = ms + (g - node * cnt);
            const float4* src = (const float4*)(out + ((size_t)node * SH_DIM + mm) * C_DIM + q * 32);
            unsigned short tmp[32];
            #pragma unroll
            for (int v = 0; v < 8; ++v) {
                float4 fv = src[v];
                tmp[v * 4 + 0] = bf16bits(fv.x);
                tmp[v * 4 + 1] = bf16bits(fv.y);
                tmp[v * 4 + 2] = bf16bits(fv.z);
                tmp[v * 4 + 3] = bf16bits(fv.w);
            }
            #pragma unroll
            for (int v = 0; v < 4; ++v)
                *(short8*)&As[r * 136 + q * 32 + v * 8] = *(short8*)&tmp[v * 8];
        }
        __syncthreads();      // A ready

        f32x4 acc[8] = {};
        #pragma unroll
        for (int ks = 0; ks < 4; ++ks) {
            short8 a = *(const short8*)&As[(wid * 16 + (lane & 15)) * 136 + ks * 32 + (lane >> 4) * 8];
            #pragma unroll
            for (int f = 0; f < 8; ++f) {
                short8 b = *(const short8*)&Bp[(f * 16 + (lane & 15)) * 136 + ks * 32 + (lane >> 4) * 8];
                acc[f] = __builtin_amdgcn_mfma_f32_16x16x32_bf16(a, b, acc[f], 0, 0, 0);
            }
        }
        __syncthreads();      // all A reads done before next iter's staging

        // direct stores: row = wid*16 + (lane>>4)*4 + r ; col = f*16 + (lane&15)
        #pragma unroll
        for (int r = 0; r < 4; ++r) {
            int g = i0 + wid * 16 + (lane >> 4) * 4 + r;
            if (g < M) {
                int node = g / cnt, mm = ms + (g - node * cnt);
                float* dst = out + ((size_t)node * SH_DIM + mm) * C_DIM + (lane & 15);
                #pragma unroll
                for (int f = 0; f < 8; ++f)
                    dst[f * 16] = acc[f][r];
            }
        }
    }
}

extern "C" void kernel_launch(void* const* d_in, const int* in_sizes, int n_in,
                              void* d_out, int out_size, void* d_ws, size_t ws_size,
                              hipStream_t stream)
{
    const float* node_attrs = (const float*)d_in[0];
    const float* node_feats = (const float*)d_in[1];
    const float* edge_attrs = (const float*)d_in[2];
    const float* edge_feats = (const float*)d_in[3];
    const int*   edge_index = (const int*)d_in[4];
    const float* w_up   = (const float*)d_in[5];
    const float* w_rad1 = (const float*)d_in[6];
    const float* w_rad2 = (const float*)d_in[7];
    const float* w_rad3 = (const float*)d_in[8];
    const float* w_rad4 = (const float*)d_in[9];
    const float* w_skip = (const float*)d_in[10];
    const float* w_out  = (const float*)d_in[11];
    const int* sender = edge_index;
    const int* recv   = edge_index + N_EDGE;

    float* out = (float*)d_out;                                 // msg staged here, then in-place
    float* sc  = out + (size_t)N_NODES * SH_DIM * C_DIM;

    // workspace layout (ws >= 233.4 MB proven; this needs ~138 MB)
    float* x   = (float*)d_ws;
    float* h3  = x + (size_t)N_NODES * C_DIM;
    int* deg    = (int*)(h3 + (size_t)N_EDGE * RAD_H);
    int* cursor = deg + 5120;
    int* offs   = cursor + 5120;
    int* perm   = offs + 5124;
    __hip_bfloat16* tpw = (__hip_bfloat16*)(perm + N_EDGE);
    int* sid_arr = (int*)(tpw + (size_t)N_EDGE * NL * C_DIM);
    float* ea_perm = (float*)(sid_arr + N_EDGE);
    size_t need = (size_t)((char*)(ea_perm + (size_t)N_EDGE * SH_DIM) - (char*)d_ws);
    int mode = (ws_size >= need) ? 1 : 0;

    hipMemsetAsync(deg, 0, 2 * 5120 * sizeof(int), stream);

    node_kernel<<<N_NODES, 128, 0, stream>>>(node_attrs, node_feats, w_skip, w_up, x, sc);
    radial_kernel<<<1024, 256, 0, stream>>>(edge_feats, w_rad1, w_rad2, w_rad3, h3);

    hist_kernel<<<(N_EDGE + 255) / 256, 256, 0, stream>>>(recv, deg);
    scan_kernel<<<1, 256, 0, stream>>>(deg, offs);
    scatter_kernel<<<(N_EDGE + 255) / 256, 256, 0, stream>>>(recv, offs, cursor, perm);

    if (mode == 1) {
        reorder_kernel<<<(N_EDGE + 255) / 256, 256, 0, stream>>>(perm, sender, edge_attrs, sid_arr, (float4*)ea_perm);
        tpw_gemm_kernel<<<dim3(391, 4), 256, 0, stream>>>(perm, h3, w_rad4, tpw);
        stream_gather_kernel<<<N_NODES, 256, 0, stream>>>(offs, sid_arr, x, ea_perm, tpw, out);
    } else {
        fused_gather_kernel<<<N_NODES, 512, 0, stream>>>(perm, offs, sender, x, edge_attrs, h3, w_rad4, out);
    }

    out_mfma_kernel<<<dim3(547, 4), 256, 0, stream>>>(out, w_out);
}

// Round 21
// 243.378 us; speedup vs baseline: 1.5067x; 1.2372x over previous
//
#include <hip/hip_runtime.h>
#include <hip/hip_bf16.h>
#include <math.h>

#define N_NODES 5000
#define N_ELEMS 10
#define C_DIM   128
#define N_EDGE  100000
#define N_BES   8
#define RAD_H   64
#define NL      4
#define SH_DIM  16
#define TPW_ROWS 64

// scales
#define SC_SCALE 0.02795084971874737f    // 1/sqrt(128*10)
#define X_SCALE  0.08838834764831845f    // 1/sqrt(128)
#define R1_SCALE 0.3535533905932738f     // 1/sqrt(8)
#define R_SCALE  0.125f                  // 1/sqrt(64)
#define OUT_SCALE 0.004419417382415922f  // (1/sqrt(128))/20

typedef __attribute__((ext_vector_type(8))) short short8;
typedef __attribute__((ext_vector_type(4))) float f32x4;

__device__ __forceinline__ float silu(float v) { return v / (1.f + __expf(-v)); }
__device__ __forceinline__ unsigned short bf16bits(float v) {
    __hip_bfloat16 h = __float2bfloat16(v);
    return *(unsigned short*)&h;
}

// ---------------- node kernel: sc + x ----------------
__global__ __launch_bounds__(128) void node_kernel(
    const float* __restrict__ node_attrs, const float* __restrict__ node_feats,
    const float* __restrict__ w_skip, const float* __restrict__ w_up,
    float* __restrict__ x, float* __restrict__ sc_out)
{
    int n = blockIdx.x, t = threadIdx.x;
    __shared__ float f[C_DIM];
    __shared__ float at[N_ELEMS];
    f[t] = node_feats[(size_t)n * C_DIM + t];
    if (t < N_ELEMS) at[t] = node_attrs[(size_t)n * N_ELEMS + t];
    __syncthreads();

    float acc = 0.f;
    for (int a = 0; a < N_ELEMS; ++a) {
        float av = at[a];
        if (av != 0.f) {
            const float* wp = w_skip + a * C_DIM + t;
            float s2 = 0.f;
            #pragma unroll 8
            for (int c = 0; c < C_DIM; ++c) s2 += f[c] * wp[(size_t)c * (N_ELEMS * C_DIM)];
            acc += av * s2;
        }
    }
    sc_out[(size_t)n * C_DIM + t] = acc * SC_SCALE;

    float xa = 0.f;
    #pragma unroll 8
    for (int k = 0; k < C_DIM; ++k) xa += f[k] * w_up[k * C_DIM + t];
    x[(size_t)n * C_DIM + t] = xa * X_SCALE;
}

// ---------------- radial MLP v3: MFMA for layers 2+3 ----------------
// Round-20 lesson: barrier removal was a null fix - the kernel is
// LDS-instruction-bound (64 scalar ds_read_b32 weight reads + addr calc per
// edge per layer). Layers 2/3 are 64x64 GEMMs -> matrix cores.
// 64-edge tile/block, 4 waves x 16 edges. Layer1 VALU (w1 col in regs,
// ef via uniform s_loads). A rows are wave-exclusive -> in-place As reuse,
// no block barriers in the loop. Fragment layouts verbatim from verified
// tpw_gemm (m89).
__global__ __launch_bounds__(256, 2) void radial_mfma_kernel(
    const float* __restrict__ edge_feats,
    const float* __restrict__ w1, const float* __restrict__ w2, const float* __restrict__ w3,
    float* __restrict__ h3out)
{
    __shared__ unsigned short As[64 * 72];    // [edge][k] bf16, pad 8 (9.2 KB)
    __shared__ unsigned short w2t[64 * 72];   // [n][k] bf16, R_SCALE folded
    __shared__ unsigned short w3t[64 * 72];
    int t = threadIdx.x;
    int lane = t & 63, wid = t >> 6;

    // stage transposed bf16 weight panels (R_SCALE folded)
    for (int idx = t; idx < RAD_H * RAD_H; idx += 256) {
        int k = idx >> 6, n = idx & 63;
        w2t[n * 72 + k] = bf16bits(w2[k * RAD_H + n] * R_SCALE);
        w3t[n * 72 + k] = bf16bits(w3[k * RAD_H + n] * R_SCALE);
    }
    __syncthreads();     // the only block barrier

    // hoist B fragments to registers: n = f*16+(lane&15), k = s*32+(lane>>4)*8
    short8 b2[2][4], b3[2][4];
    #pragma unroll
    for (int s = 0; s < 2; ++s)
        #pragma unroll
        for (int f = 0; f < 4; ++f) {
            b2[s][f] = *(const short8*)&w2t[(f * 16 + (lane & 15)) * 72 + s * 32 + (lane >> 4) * 8];
            b3[s][f] = *(const short8*)&w3t[(f * 16 + (lane & 15)) * 72 + s * 32 + (lane >> 4) * 8];
        }

    // layer-1 weights: column j=lane in registers, R1_SCALE folded
    float w1r[N_BES];
    #pragma unroll
    for (int k = 0; k < N_BES; ++k) w1r[k] = w1[k * RAD_H + lane] * R1_SCALE;

    const int ntiles = (N_EDGE + 63) >> 6;   // 1563
    for (int tile = blockIdx.x; tile < ntiles; tile += gridDim.x) {
        int i0 = tile << 6;
        int ebase = __builtin_amdgcn_readfirstlane(i0 + wid * 16);

        // ---- layer 1: h1[e][lane] for this wave's 16 edges ----
        #pragma unroll 4
        for (int ee = 0; ee < 16; ++ee) {
            int e = min(ebase + ee, N_EDGE - 1);
            const float* ef = edge_feats + (size_t)e * N_BES;   // uniform -> s_load
            float a = 0.f;
            #pragma unroll
            for (int k = 0; k < N_BES; ++k) a += ef[k] * w1r[k];
            As[(wid * 16 + ee) * 72 + lane] = bf16bits(silu(a));
        }
        __builtin_amdgcn_wave_barrier();

        // ---- layer 2: [16 x 64] @ w2 -> silu -> As in place ----
        {
            short8 a0 = *(const short8*)&As[(wid * 16 + (lane & 15)) * 72 + 0 * 32 + (lane >> 4) * 8];
            short8 a1 = *(const short8*)&As[(wid * 16 + (lane & 15)) * 72 + 1 * 32 + (lane >> 4) * 8];
            f32x4 acc[4] = {};
            #pragma unroll
            for (int f = 0; f < 4; ++f) {
                acc[f] = __builtin_amdgcn_mfma_f32_16x16x32_bf16(a0, b2[0][f], acc[f], 0, 0, 0);
                acc[f] = __builtin_amdgcn_mfma_f32_16x16x32_bf16(a1, b2[1][f], acc[f], 0, 0, 0);
            }
            __builtin_amdgcn_wave_barrier();   // all A reads done before overwrite
            #pragma unroll
            for (int f = 0; f < 4; ++f)
                #pragma unroll
                for (int r = 0; r < 4; ++r)
                    As[(wid * 16 + (lane >> 4) * 4 + r) * 72 + f * 16 + (lane & 15)] =
                        bf16bits(silu(acc[f][r]));
        }
        __builtin_amdgcn_wave_barrier();

        // ---- layer 3: -> silu -> h3 global (f32) ----
        {
            short8 a0 = *(const short8*)&As[(wid * 16 + (lane & 15)) * 72 + 0 * 32 + (lane >> 4) * 8];
            short8 a1 = *(const short8*)&As[(wid * 16 + (lane & 15)) * 72 + 1 * 32 + (lane >> 4) * 8];
            f32x4 acc[4] = {};
            #pragma unroll
            for (int f = 0; f < 4; ++f) {
                acc[f] = __builtin_amdgcn_mfma_f32_16x16x32_bf16(a0, b3[0][f], acc[f], 0, 0, 0);
                acc[f] = __builtin_amdgcn_mfma_f32_16x16x32_bf16(a1, b3[1][f], acc[f], 0, 0, 0);
            }
            #pragma unroll
            for (int r = 0; r < 4; ++r) {
                int e = i0 + wid * 16 + (lane >> 4) * 4 + r;
                if (e < N_EDGE) {
                    float* dst = h3out + (size_t)e * RAD_H + (lane & 15);
                    #pragma unroll
                    for (int f = 0; f < 4; ++f)
                        dst[f * 16] = silu(acc[f][r]);
                }
            }
        }
        __builtin_amdgcn_wave_barrier();   // WAR fence before next tile's layer-1 writes
    }
}

// ---------------- CSR build ----------------
__global__ void hist_kernel(const int* __restrict__ recv, int* __restrict__ deg)
{
    int e = blockIdx.x * 256 + threadIdx.x;
    if (e < N_EDGE) atomicAdd(&deg[recv[e]], 1);
}

__global__ __launch_bounds__(256) void scan_kernel(const int* __restrict__ deg, int* __restrict__ offs)
{
    __shared__ int sums[256];
    int t = threadIdx.x;
    int base = t * 20;
    int loc[20]; int s = 0;
    #pragma unroll
    for (int i = 0; i < 20; ++i) { int idx = base + i; int v = (idx < N_NODES) ? deg[idx] : 0; loc[i] = s; s += v; }
    sums[t] = s; __syncthreads();
    for (int off = 1; off < 256; off <<= 1) {
        int v = (t >= off) ? sums[t - off] : 0;
        __syncthreads();
        sums[t] += v;
        __syncthreads();
    }
    int ex = (t == 0) ? 0 : sums[t - 1];
    #pragma unroll
    for (int i = 0; i < 20; ++i) { int idx = base + i; if (idx < N_NODES) offs[idx] = ex + loc[i]; }
    if (t == 255) offs[N_NODES] = sums[255];
}

__global__ void scatter_kernel(const int* __restrict__ recv, const int* __restrict__ offs,
                               int* __restrict__ cursor, int* __restrict__ perm)
{
    int e = blockIdx.x * 256 + threadIdx.x;
    if (e < N_EDGE) {
        int r = recv[e];
        int pos = atomicAdd(&cursor[r], 1);
        perm[offs[r] + pos] = e;
    }
}

// ---------------- reorder: sid_arr[idx]=sender[perm[idx]], ea_perm[idx]=edge_attrs[perm[idx]] ----------------
__global__ void reorder_kernel(const int* __restrict__ perm, const int* __restrict__ sender,
                               const float* __restrict__ edge_attrs,
                               int* __restrict__ sid_arr, float4* __restrict__ ea_perm4)
{
    int idx = blockIdx.x * 256 + threadIdx.x;
    if (idx < N_EDGE) {
        int e = perm[idx];
        sid_arr[idx] = sender[e];
        const float4* src = (const float4*)(edge_attrs + (size_t)e * SH_DIM);
        float4* dst = ea_perm4 + (size_t)idx * 4;
        dst[0] = src[0]; dst[1] = src[1]; dst[2] = src[2]; dst[3] = src[3];
    }
}

// ---------------- tpw GEMM via MFMA (bf16): tpw[i,:] = h3[perm[i],:] @ w4*R_SCALE ----------------
__global__ __launch_bounds__(256, 2) void tpw_gemm_kernel(
    const int* __restrict__ perm, const float* __restrict__ h3,
    const float* __restrict__ w4, __hip_bfloat16* __restrict__ tpw)
{
    __shared__ unsigned short As[64 * 72];
    __shared__ unsigned short Bp[128 * 72];
    __shared__ unsigned short epi[64 * 136];
    int l = blockIdx.y, t = threadIdx.x;
    int lane = t & 63, wid = t >> 6;

    for (int idx = t; idx < RAD_H * C_DIM; idx += 256) {
        int k = idx >> 7, n = idx & 127;
        Bp[n * 72 + k] = bf16bits(w4[k * (NL * C_DIM) + l * C_DIM + n] * R_SCALE);
    }
    __syncthreads();

    short8 bfr[2][8];
    #pragma unroll
    for (int s = 0; s < 2; ++s)
        #pragma unroll
        for (int f = 0; f < 8; ++f)
            bfr[s][f] = *(const short8*)&Bp[(f * 16 + (lane & 15)) * 72 + s * 32 + (lane >> 4) * 8];

    const int ntiles = (N_EDGE + TPW_ROWS - 1) / TPW_ROWS;
    for (int tile = blockIdx.x; tile < ntiles; tile += gridDim.x) {
        int i0 = tile * TPW_ROWS;
        {
            int r = t >> 2, q = t & 3;
            int e = perm[min(i0 + r, N_EDGE - 1)];
            const float4* src = (const float4*)(h3 + (size_t)e * RAD_H + q * 16);
            unsigned short tmp[16];
            #pragma unroll
            for (int v = 0; v < 4; ++v) {
                float4 fv = src[v];
                tmp[v * 4 + 0] = bf16bits(fv.x);
                tmp[v * 4 + 1] = bf16bits(fv.y);
                tmp[v * 4 + 2] = bf16bits(fv.z);
                tmp[v * 4 + 3] = bf16bits(fv.w);
            }
            *(short8*)&As[r * 72 + q * 16]     = *(short8*)&tmp[0];
            *(short8*)&As[r * 72 + q * 16 + 8] = *(short8*)&tmp[8];
        }
        __syncthreads();

        f32x4 acc[8] = {};
        #pragma unroll
        for (int s = 0; s < 2; ++s) {
            short8 a = *(const short8*)&As[(wid * 16 + (lane & 15)) * 72 + s * 32 + (lane >> 4) * 8];
            #pragma unroll
            for (int f = 0; f < 8; ++f)
                acc[f] = __builtin_amdgcn_mfma_f32_16x16x32_bf16(a, bfr[s][f], acc[f], 0, 0, 0);
        }
        #pragma unroll
        for (int f = 0; f < 8; ++f)
            #pragma unroll
            for (int r = 0; r < 4; ++r)
                epi[(wid * 16 + (lane >> 4) * 4 + r) * 136 + f * 16 + (lane & 15)] = bf16bits(acc[f][r]);
        __syncthreads();

        {
            int row = t >> 2, q = t & 3;
            if (i0 + row < N_EDGE) {
                unsigned short* dst = (unsigned short*)tpw + (size_t)(i0 + row) * (NL * C_DIM) + l * C_DIM + q * 32;
                #pragma unroll
                for (int v = 0; v < 4; ++v)
                    *(short8*)(dst + v * 8) = *(const short8*)&epi[row * 136 + q * 32 + v * 8];
            }
        }
    }
}

// ---------------- stream gather v3: 256 thr (l=t>>6 wave-uniform, 2 c's/thread) ----------------
__global__ __launch_bounds__(256, 4) void stream_gather_kernel(
    const int* __restrict__ offs, const int* __restrict__ sid_arr,
    const float* __restrict__ x, const float* __restrict__ ea_perm,
    const __hip_bfloat16* __restrict__ tpw, float* __restrict__ msg)
{
    int n = blockIdx.x, t = threadIdx.x;
    int cq = t & 63, l = t >> 6;
    int c0 = cq * 2;
    float acc[7][2] = {};
    int nm = 2 * l + 1;
    int start = offs[n], end = offs[n + 1];

    for (int base = start; base < end; base += 4) {
        int idxb[4], sidb[4];
        #pragma unroll
        for (int j = 0; j < 4; ++j) idxb[j] = min(base + j, end - 1);
        #pragma unroll
        for (int j = 0; j < 4; ++j) sidb[j] = sid_arr[idxb[j]];

        unsigned int tpb[4];
        float2 xv[4];
        #pragma unroll
        for (int j = 0; j < 4; ++j)
            tpb[j] = *(const unsigned int*)((const unsigned short*)tpw + (size_t)idxb[j] * (NL * C_DIM) + l * C_DIM + c0);
        #pragma unroll
        for (int j = 0; j < 4; ++j)
            xv[j] = *(const float2*)(x + (size_t)sidb[j] * C_DIM + c0);
        asm volatile("" : "+v"(tpb[0]), "+v"(tpb[1]), "+v"(tpb[2]), "+v"(tpb[3]),
                          "+v"(xv[0].x), "+v"(xv[0].y), "+v"(xv[1].x), "+v"(xv[1].y),
                          "+v"(xv[2].x), "+v"(xv[2].y), "+v"(xv[3].x), "+v"(xv[3].y));

        #pragma unroll
        for (int j = 0; j < 4; ++j) {
            unsigned int lo = (tpb[j] & 0xFFFFu) << 16;
            unsigned int hi = tpb[j] & 0xFFFF0000u;
            float tp0 = __uint_as_float(lo);
            float tp1 = __uint_as_float(hi);
            bool valid = (base + j < end);
            float xt0 = valid ? tp0 * xv[j].x : 0.f;
            float xt1 = valid ? tp1 * xv[j].y : 0.f;
            const float* ear = ea_perm + (size_t)idxb[j] * SH_DIM + l * l;
            #pragma unroll
            for (int m = 0; m < 7; ++m)
                if (m < nm) { acc[m][0] += ear[m] * xt0; acc[m][1] += ear[m] * xt1; }
        }
    }
    float* mout = msg + (size_t)n * (SH_DIM * C_DIM) + (size_t)(l * l) * C_DIM + c0;
    #pragma unroll
    for (int m = 0; m < 7; ++m)
        if (m < nm) *(float2*)(mout + (size_t)m * C_DIM) = make_float2(acc[m][0], acc[m][1]);
}

// ---------------- fallback fused gather (round-7, e-indexed) ----------------
__global__ __launch_bounds__(512, 4) void fused_gather_kernel(
    const int* __restrict__ perm, const int* __restrict__ offs,
    const int* __restrict__ sender, const float* __restrict__ x,
    const float* __restrict__ edge_attrs, const float* __restrict__ h3,
    const float* __restrict__ w4, float* __restrict__ msg)
{
    int n = blockIdx.x, t = threadIdx.x;
    int c = t & 127, l = t >> 7;
    float wc[RAD_H];
    #pragma unroll
    for (int k = 0; k < RAD_H; ++k)
        wc[k] = w4[k * (NL * C_DIM) + l * C_DIM + c];

    float acc[7] = {0.f, 0.f, 0.f, 0.f, 0.f, 0.f, 0.f};
    int nm = 2 * l + 1;
    int start = offs[n], end = offs[n + 1];
    if (start < end) {
        int e = __builtin_amdgcn_readfirstlane(perm[start]);
        int s = __builtin_amdgcn_readfirstlane(sender[e]);
        for (int idx = start; idx < end; ++idx) {
            #pragma unroll
            for (int k = 0; k < RAD_H; k += 8)
                asm volatile("" : "+v"(wc[k]), "+v"(wc[k+1]), "+v"(wc[k+2]), "+v"(wc[k+3]),
                                  "+v"(wc[k+4]), "+v"(wc[k+5]), "+v"(wc[k+6]), "+v"(wc[k+7]));
            int e_cur = e, s_cur = s;
            if (idx + 1 < end) {
                e = __builtin_amdgcn_readfirstlane(perm[idx + 1]);
                s = __builtin_amdgcn_readfirstlane(sender[e]);
            }
            const float* h3r = h3 + (size_t)e_cur * RAD_H;
            float xv = x[(size_t)s_cur * C_DIM + c];
            float tp0 = 0.f, tp1 = 0.f, tp2 = 0.f, tp3 = 0.f;
            #pragma unroll
            for (int q = 0; q < RAD_H / 4; ++q) {
                tp0 += h3r[4 * q + 0] * wc[4 * q + 0];
                tp1 += h3r[4 * q + 1] * wc[4 * q + 1];
                tp2 += h3r[4 * q + 2] * wc[4 * q + 2];
                tp3 += h3r[4 * q + 3] * wc[4 * q + 3];
            }
            float tp = (tp0 + tp1) + (tp2 + tp3);
            float xt = xv * (tp * R_SCALE);
            const float* ear = edge_attrs + (size_t)e_cur * SH_DIM + l * l;
            #pragma unroll
            for (int j = 0; j < 7; ++j)
                if (j < nm) acc[j] += ear[j] * xt;
        }
    }
    float* mout = msg + (size_t)n * (SH_DIM * C_DIM) + (size_t)(l * l) * C_DIM + c;
    #pragma unroll
    for (int j = 0; j < 7; ++j)
        if (j < nm) mout[(size_t)j * C_DIM] = acc[j];
}

// ---------------- out transform via MFMA: per l, [M_l x 128] @ w_out[l] (in place on d_out) ----------------
__global__ __launch_bounds__(256, 2) void out_mfma_kernel(
    float* __restrict__ out, const float* __restrict__ w_out)
{
    __shared__ unsigned short As[64 * 136];
    __shared__ unsigned short Bp[128 * 136];
    int l = blockIdx.y, t = threadIdx.x;
    int lane = t & 63, wid = t >> 6;
    const int cnt = 2 * l + 1, ms = l * l;
    const int M = N_NODES * cnt;
    const int ntile = (M + 63) >> 6;
    if (blockIdx.x >= ntile) return;

    for (int idx = t; idx < C_DIM * C_DIM; idx += 256) {
        int k = idx >> 7, n = idx & 127;
        Bp[n * 136 + k] = bf16bits(w_out[((size_t)l * C_DIM + k) * C_DIM + n] * OUT_SCALE);
    }
    __syncthreads();

    for (int tile = blockIdx.x; tile < ntile; tile += gridDim.x) {
        int i0 = tile << 6;
        {
            int r = t >> 2, q = t & 3;
            int g = min(i0 + r, M - 1);
            int node = g / cnt, mm = ms + (g - node * cnt);
            const float4* src = (const float4*)(out + ((size_t)node * SH_DIM + mm) * C_DIM + q * 32);
            unsigned short tmp[32];
            #pragma unroll
            for (int v = 0; v < 8; ++v) {
                float4 fv = src[v];
                tmp[v * 4 + 0] = bf16bits(fv.x);
                tmp[v * 4 + 1] = bf16bits(fv.y);
                tmp[v * 4 + 2] = bf16bits(fv.z);
                tmp[v * 4 + 3] = bf16bits(fv.w);
            }
            #pragma unroll
            for (int v = 0; v < 4; ++v)
                *(short8*)&As[r * 136 + q * 32 + v * 8] = *(short8*)&tmp[v * 8];
        }
        __syncthreads();

        f32x4 acc[8] = {};
        #pragma unroll
        for (int ks = 0; ks < 4; ++ks) {
            short8 a = *(const short8*)&As[(wid * 16 + (lane & 15)) * 136 + ks * 32 + (lane >> 4) * 8];
            #pragma unroll
            for (int f = 0; f < 8; ++f) {
                short8 b = *(const short8*)&Bp[(f * 16 + (lane & 15)) * 136 + ks * 32 + (lane >> 4) * 8];
                acc[f] = __builtin_amdgcn_mfma_f32_16x16x32_bf16(a, b, acc[f], 0, 0, 0);
            }
        }
        __syncthreads();

        #pragma unroll
        for (int r = 0; r < 4; ++r) {
            int g = i0 + wid * 16 + (lane >> 4) * 4 + r;
            if (g < M) {
                int node = g / cnt, mm = ms + (g - node * cnt);
                float* dst = out + ((size_t)node * SH_DIM + mm) * C_DIM + (lane & 15);
                #pragma unroll
                for (int f = 0; f < 8; ++f)
                    dst[f * 16] = acc[f][r];
            }
        }
    }
}

extern "C" void kernel_launch(void* const* d_in, const int* in_sizes, int n_in,
                              void* d_out, int out_size, void* d_ws, size_t ws_size,
                              hipStream_t stream)
{
    const float* node_attrs = (const float*)d_in[0];
    const float* node_feats = (const float*)d_in[1];
    const float* edge_attrs = (const float*)d_in[2];
    const float* edge_feats = (const float*)d_in[3];
    const int*   edge_index = (const int*)d_in[4];
    const float* w_up   = (const float*)d_in[5];
    const float* w_rad1 = (const float*)d_in[6];
    const float* w_rad2 = (const float*)d_in[7];
    const float* w_rad3 = (const float*)d_in[8];
    const float* w_rad4 = (const float*)d_in[9];
    const float* w_skip = (const float*)d_in[10];
    const float* w_out  = (const float*)d_in[11];
    const int* sender = edge_index;
    const int* recv   = edge_index + N_EDGE;

    float* out = (float*)d_out;                                 // msg staged here, then in-place
    float* sc  = out + (size_t)N_NODES * SH_DIM * C_DIM;

    // workspace layout (ws >= 233.4 MB proven; this needs ~138 MB)
    float* x   = (float*)d_ws;
    float* h3  = x + (size_t)N_NODES * C_DIM;
    int* deg    = (int*)(h3 + (size_t)N_EDGE * RAD_H);
    int* cursor = deg + 5120;
    int* offs   = cursor + 5120;
    int* perm   = offs + 5124;
    __hip_bfloat16* tpw = (__hip_bfloat16*)(perm + N_EDGE);
    int* sid_arr = (int*)(tpw + (size_t)N_EDGE * NL * C_DIM);
    float* ea_perm = (float*)(sid_arr + N_EDGE);
    size_t need = (size_t)((char*)(ea_perm + (size_t)N_EDGE * SH_DIM) - (char*)d_ws);
    int mode = (ws_size >= need) ? 1 : 0;

    hipMemsetAsync(deg, 0, 2 * 5120 * sizeof(int), stream);

    node_kernel<<<N_NODES, 128, 0, stream>>>(node_attrs, node_feats, w_skip, w_up, x, sc);
    radial_mfma_kernel<<<391, 256, 0, stream>>>(edge_feats, w_rad1, w_rad2, w_rad3, h3);

    hist_kernel<<<(N_EDGE + 255) / 256, 256, 0, stream>>>(recv, deg);
    scan_kernel<<<1, 256, 0, stream>>>(deg, offs);
    scatter_kernel<<<(N_EDGE + 255) / 256, 256, 0, stream>>>(recv, offs, cursor, perm);

    if (mode == 1) {
        reorder_kernel<<<(N_EDGE + 255) / 256, 256, 0, stream>>>(perm, sender, edge_attrs, sid_arr, (float4*)ea_perm);
        tpw_gemm_kernel<<<dim3(391, 4), 256, 0, stream>>>(perm, h3, w_rad4, tpw);
        stream_gather_kernel<<<N_NODES, 256, 0, stream>>>(offs, sid_arr, x, ea_perm, tpw, out);
    } else {
        fused_gather_kernel<<<N_NODES, 512, 0, stream>>>(perm, offs, sender, x, edge_attrs, h3, w_rad4, out);
    }

    out_mfma_kernel<<<dim3(547, 4), 256, 0, stream>>>(out, w_out);
}

// Round 22
// 241.158 us; speedup vs baseline: 1.5205x; 1.0092x over previous
//
#include <hip/hip_runtime.h>
#include <hip/hip_bf16.h>
#include <math.h>

#define N_NODES 5000
#define N_ELEMS 10
#define C_DIM   128
#define N_EDGE  100000
#define N_BES   8
#define RAD_H   64
#define NL      4
#define SH_DIM  16
#define TPW_ROWS 64

// scales
#define SC_SCALE 0.02795084971874737f    // 1/sqrt(128*10)
#define X_SCALE  0.08838834764831845f    // 1/sqrt(128)
#define R1_SCALE 0.3535533905932738f     // 1/sqrt(8)
#define R_SCALE  0.125f                  // 1/sqrt(64)
#define OUT_SCALE 0.004419417382415922f  // (1/sqrt(128))/20

typedef __attribute__((ext_vector_type(8))) short short8;
typedef __attribute__((ext_vector_type(4))) float f32x4;

__device__ __forceinline__ float silu(float v) { return v / (1.f + __expf(-v)); }
__device__ __forceinline__ unsigned short bf16bits(float v) {
    __hip_bfloat16 h = __float2bfloat16(v);
    return *(unsigned short*)&h;
}

// ---------------- node kernel: sc + x ----------------
__global__ __launch_bounds__(128) void node_kernel(
    const float* __restrict__ node_attrs, const float* __restrict__ node_feats,
    const float* __restrict__ w_skip, const float* __restrict__ w_up,
    float* __restrict__ x, float* __restrict__ sc_out)
{
    int n = blockIdx.x, t = threadIdx.x;
    __shared__ float f[C_DIM];
    __shared__ float at[N_ELEMS];
    f[t] = node_feats[(size_t)n * C_DIM + t];
    if (t < N_ELEMS) at[t] = node_attrs[(size_t)n * N_ELEMS + t];
    __syncthreads();

    float acc = 0.f;
    for (int a = 0; a < N_ELEMS; ++a) {
        float av = at[a];
        if (av != 0.f) {
            const float* wp = w_skip + a * C_DIM + t;
            float s2 = 0.f;
            #pragma unroll 8
            for (int c = 0; c < C_DIM; ++c) s2 += f[c] * wp[(size_t)c * (N_ELEMS * C_DIM)];
            acc += av * s2;
        }
    }
    sc_out[(size_t)n * C_DIM + t] = acc * SC_SCALE;

    float xa = 0.f;
    #pragma unroll 8
    for (int k = 0; k < C_DIM; ++k) xa += f[k] * w_up[k * C_DIM + t];
    x[(size_t)n * C_DIM + t] = xa * X_SCALE;
}

// ---------------- radial MLP v3: MFMA for layers 2+3 ----------------
__global__ __launch_bounds__(256, 2) void radial_mfma_kernel(
    const float* __restrict__ edge_feats,
    const float* __restrict__ w1, const float* __restrict__ w2, const float* __restrict__ w3,
    float* __restrict__ h3out)
{
    __shared__ unsigned short As[64 * 72];
    __shared__ unsigned short w2t[64 * 72];
    __shared__ unsigned short w3t[64 * 72];
    int t = threadIdx.x;
    int lane = t & 63, wid = t >> 6;

    for (int idx = t; idx < RAD_H * RAD_H; idx += 256) {
        int k = idx >> 6, n = idx & 63;
        w2t[n * 72 + k] = bf16bits(w2[k * RAD_H + n] * R_SCALE);
        w3t[n * 72 + k] = bf16bits(w3[k * RAD_H + n] * R_SCALE);
    }
    __syncthreads();

    short8 b2[2][4], b3[2][4];
    #pragma unroll
    for (int s = 0; s < 2; ++s)
        #pragma unroll
        for (int f = 0; f < 4; ++f) {
            b2[s][f] = *(const short8*)&w2t[(f * 16 + (lane & 15)) * 72 + s * 32 + (lane >> 4) * 8];
            b3[s][f] = *(const short8*)&w3t[(f * 16 + (lane & 15)) * 72 + s * 32 + (lane >> 4) * 8];
        }

    float w1r[N_BES];
    #pragma unroll
    for (int k = 0; k < N_BES; ++k) w1r[k] = w1[k * RAD_H + lane] * R1_SCALE;

    const int ntiles = (N_EDGE + 63) >> 6;
    for (int tile = blockIdx.x; tile < ntiles; tile += gridDim.x) {
        int i0 = tile << 6;
        int ebase = __builtin_amdgcn_readfirstlane(i0 + wid * 16);

        #pragma unroll 4
        for (int ee = 0; ee < 16; ++ee) {
            int e = min(ebase + ee, N_EDGE - 1);
            const float* ef = edge_feats + (size_t)e * N_BES;
            float a = 0.f;
            #pragma unroll
            for (int k = 0; k < N_BES; ++k) a += ef[k] * w1r[k];
            As[(wid * 16 + ee) * 72 + lane] = bf16bits(silu(a));
        }
        __builtin_amdgcn_wave_barrier();

        {
            short8 a0 = *(const short8*)&As[(wid * 16 + (lane & 15)) * 72 + 0 * 32 + (lane >> 4) * 8];
            short8 a1 = *(const short8*)&As[(wid * 16 + (lane & 15)) * 72 + 1 * 32 + (lane >> 4) * 8];
            f32x4 acc[4] = {};
            #pragma unroll
            for (int f = 0; f < 4; ++f) {
                acc[f] = __builtin_amdgcn_mfma_f32_16x16x32_bf16(a0, b2[0][f], acc[f], 0, 0, 0);
                acc[f] = __builtin_amdgcn_mfma_f32_16x16x32_bf16(a1, b2[1][f], acc[f], 0, 0, 0);
            }
            __builtin_amdgcn_wave_barrier();
            #pragma unroll
            for (int f = 0; f < 4; ++f)
                #pragma unroll
                for (int r = 0; r < 4; ++r)
                    As[(wid * 16 + (lane >> 4) * 4 + r) * 72 + f * 16 + (lane & 15)] =
                        bf16bits(silu(acc[f][r]));
        }
        __builtin_amdgcn_wave_barrier();

        {
            short8 a0 = *(const short8*)&As[(wid * 16 + (lane & 15)) * 72 + 0 * 32 + (lane >> 4) * 8];
            short8 a1 = *(const short8*)&As[(wid * 16 + (lane & 15)) * 72 + 1 * 32 + (lane >> 4) * 8];
            f32x4 acc[4] = {};
            #pragma unroll
            for (int f = 0; f < 4; ++f) {
                acc[f] = __builtin_amdgcn_mfma_f32_16x16x32_bf16(a0, b3[0][f], acc[f], 0, 0, 0);
                acc[f] = __builtin_amdgcn_mfma_f32_16x16x32_bf16(a1, b3[1][f], acc[f], 0, 0, 0);
            }
            #pragma unroll
            for (int r = 0; r < 4; ++r) {
                int e = i0 + wid * 16 + (lane >> 4) * 4 + r;
                if (e < N_EDGE) {
                    float* dst = h3out + (size_t)e * RAD_H + (lane & 15);
                    #pragma unroll
                    for (int f = 0; f < 4; ++f)
                        dst[f * 16] = silu(acc[f][r]);
                }
            }
        }
        __builtin_amdgcn_wave_barrier();
    }
}

// ---------------- CSR build ----------------
__global__ void hist_kernel(const int* __restrict__ recv, int* __restrict__ deg)
{
    int e = blockIdx.x * 256 + threadIdx.x;
    if (e < N_EDGE) atomicAdd(&deg[recv[e]], 1);
}

__global__ __launch_bounds__(256) void scan_kernel(const int* __restrict__ deg, int* __restrict__ offs)
{
    __shared__ int sums[256];
    int t = threadIdx.x;
    int base = t * 20;
    int loc[20]; int s = 0;
    #pragma unroll
    for (int i = 0; i < 20; ++i) { int idx = base + i; int v = (idx < N_NODES) ? deg[idx] : 0; loc[i] = s; s += v; }
    sums[t] = s; __syncthreads();
    for (int off = 1; off < 256; off <<= 1) {
        int v = (t >= off) ? sums[t - off] : 0;
        __syncthreads();
        sums[t] += v;
        __syncthreads();
    }
    int ex = (t == 0) ? 0 : sums[t - 1];
    #pragma unroll
    for (int i = 0; i < 20; ++i) { int idx = base + i; if (idx < N_NODES) offs[idx] = ex + loc[i]; }
    if (t == 255) offs[N_NODES] = sums[255];
}

__global__ void scatter_kernel(const int* __restrict__ recv, const int* __restrict__ offs,
                               int* __restrict__ cursor, int* __restrict__ perm)
{
    int e = blockIdx.x * 256 + threadIdx.x;
    if (e < N_EDGE) {
        int r = recv[e];
        int pos = atomicAdd(&cursor[r], 1);
        perm[offs[r] + pos] = e;
    }
}

// ---------------- reorder: sid_arr[idx]=sender[perm[idx]], ea_perm[idx]=edge_attrs[perm[idx]] ----------------
__global__ void reorder_kernel(const int* __restrict__ perm, const int* __restrict__ sender,
                               const float* __restrict__ edge_attrs,
                               int* __restrict__ sid_arr, float4* __restrict__ ea_perm4)
{
    int idx = blockIdx.x * 256 + threadIdx.x;
    if (idx < N_EDGE) {
        int e = perm[idx];
        sid_arr[idx] = sender[e];
        const float4* src = (const float4*)(edge_attrs + (size_t)e * SH_DIM);
        float4* dst = ea_perm4 + (size_t)idx * 4;
        dst[0] = src[0]; dst[1] = src[1]; dst[2] = src[2]; dst[3] = src[3];
    }
}

// ---------------- tpw GEMM via MFMA (bf16): tpw[i,:] = h3[perm[i],:] @ w4*R_SCALE ----------------
__global__ __launch_bounds__(256, 2) void tpw_gemm_kernel(
    const int* __restrict__ perm, const float* __restrict__ h3,
    const float* __restrict__ w4, __hip_bfloat16* __restrict__ tpw)
{
    __shared__ unsigned short As[64 * 72];
    __shared__ unsigned short Bp[128 * 72];
    __shared__ unsigned short epi[64 * 136];
    int l = blockIdx.y, t = threadIdx.x;
    int lane = t & 63, wid = t >> 6;

    for (int idx = t; idx < RAD_H * C_DIM; idx += 256) {
        int k = idx >> 7, n = idx & 127;
        Bp[n * 72 + k] = bf16bits(w4[k * (NL * C_DIM) + l * C_DIM + n] * R_SCALE);
    }
    __syncthreads();

    short8 bfr[2][8];
    #pragma unroll
    for (int s = 0; s < 2; ++s)
        #pragma unroll
        for (int f = 0; f < 8; ++f)
            bfr[s][f] = *(const short8*)&Bp[(f * 16 + (lane & 15)) * 72 + s * 32 + (lane >> 4) * 8];

    const int ntiles = (N_EDGE + TPW_ROWS - 1) / TPW_ROWS;
    for (int tile = blockIdx.x; tile < ntiles; tile += gridDim.x) {
        int i0 = tile * TPW_ROWS;
        {
            int r = t >> 2, q = t & 3;
            int e = perm[min(i0 + r, N_EDGE - 1)];
            const float4* src = (const float4*)(h3 + (size_t)e * RAD_H + q * 16);
            unsigned short tmp[16];
            #pragma unroll
            for (int v = 0; v < 4; ++v) {
                float4 fv = src[v];
                tmp[v * 4 + 0] = bf16bits(fv.x);
                tmp[v * 4 + 1] = bf16bits(fv.y);
                tmp[v * 4 + 2] = bf16bits(fv.z);
                tmp[v * 4 + 3] = bf16bits(fv.w);
            }
            *(short8*)&As[r * 72 + q * 16]     = *(short8*)&tmp[0];
            *(short8*)&As[r * 72 + q * 16 + 8] = *(short8*)&tmp[8];
        }
        __syncthreads();

        f32x4 acc[8] = {};
        #pragma unroll
        for (int s = 0; s < 2; ++s) {
            short8 a = *(const short8*)&As[(wid * 16 + (lane & 15)) * 72 + s * 32 + (lane >> 4) * 8];
            #pragma unroll
            for (int f = 0; f < 8; ++f)
                acc[f] = __builtin_amdgcn_mfma_f32_16x16x32_bf16(a, bfr[s][f], acc[f], 0, 0, 0);
        }
        #pragma unroll
        for (int f = 0; f < 8; ++f)
            #pragma unroll
            for (int r = 0; r < 4; ++r)
                epi[(wid * 16 + (lane >> 4) * 4 + r) * 136 + f * 16 + (lane & 15)] = bf16bits(acc[f][r]);
        __syncthreads();

        {
            int row = t >> 2, q = t & 3;
            if (i0 + row < N_EDGE) {
                unsigned short* dst = (unsigned short*)tpw + (size_t)(i0 + row) * (NL * C_DIM) + l * C_DIM + q * 32;
                #pragma unroll
                for (int v = 0; v < 4; ++v)
                    *(short8*)(dst + v * 8) = *(const short8*)&epi[row * 136 + q * 32 + v * 8];
            }
        }
    }
}

// ---------------- stream gather v4: 8-edge batch for 2x memory-level parallelism ----------------
// Round-21 lesson: 4-deep batch = 4 x 256B tpw loads in flight vs 900cyc HBM
// latency -> 0.86 TB/s (matches MLP model). Batch 8 doubles in-flight loads.
__global__ __launch_bounds__(256, 4) void stream_gather_kernel(
    const int* __restrict__ offs, const int* __restrict__ sid_arr,
    const float* __restrict__ x, const float* __restrict__ ea_perm,
    const __hip_bfloat16* __restrict__ tpw, float* __restrict__ msg)
{
    int n = blockIdx.x, t = threadIdx.x;
    int cq = t & 63, l = t >> 6;          // l wave-uniform; c = cq*2, cq*2+1
    int c0 = cq * 2;
    float acc[7][2] = {};
    int nm = 2 * l + 1;
    int start = offs[n], end = offs[n + 1];

    for (int base = start; base < end; base += 8) {
        int idxb[8], sidb[8];
        #pragma unroll
        for (int j = 0; j < 8; ++j) idxb[j] = min(base + j, end - 1);
        #pragma unroll
        for (int j = 0; j < 8; ++j) sidb[j] = sid_arr[idxb[j]];   // wave-uniform -> s_load

        unsigned int tpb[8];
        float2 xv[8];
        #pragma unroll
        for (int j = 0; j < 8; ++j)
            tpb[j] = *(const unsigned int*)((const unsigned short*)tpw + (size_t)idxb[j] * (NL * C_DIM) + l * C_DIM + c0);
        #pragma unroll
        for (int j = 0; j < 8; ++j)
            xv[j] = *(const float2*)(x + (size_t)sidb[j] * C_DIM + c0);
        // force all 24 loaded values live simultaneously -> 16 vmem loads in
        // flight before one waitcnt (prevents load/use re-serialization).
        asm volatile("" : "+v"(tpb[0]), "+v"(tpb[1]), "+v"(tpb[2]), "+v"(tpb[3]),
                          "+v"(tpb[4]), "+v"(tpb[5]), "+v"(tpb[6]), "+v"(tpb[7]),
                          "+v"(xv[0].x), "+v"(xv[0].y), "+v"(xv[1].x), "+v"(xv[1].y),
                          "+v"(xv[2].x), "+v"(xv[2].y), "+v"(xv[3].x), "+v"(xv[3].y),
                          "+v"(xv[4].x), "+v"(xv[4].y), "+v"(xv[5].x), "+v"(xv[5].y),
                          "+v"(xv[6].x), "+v"(xv[6].y), "+v"(xv[7].x), "+v"(xv[7].y));

        #pragma unroll
        for (int j = 0; j < 8; ++j) {
            unsigned int lo = (tpb[j] & 0xFFFFu) << 16;
            unsigned int hi = tpb[j] & 0xFFFF0000u;
            float tp0 = __uint_as_float(lo);
            float tp1 = __uint_as_float(hi);
            bool valid = (base + j < end);
            float xt0 = valid ? tp0 * xv[j].x : 0.f;
            float xt1 = valid ? tp1 * xv[j].y : 0.f;
            const float* ear = ea_perm + (size_t)idxb[j] * SH_DIM + l * l;   // wave-uniform
            #pragma unroll
            for (int m = 0; m < 7; ++m)
                if (m < nm) { acc[m][0] += ear[m] * xt0; acc[m][1] += ear[m] * xt1; }
        }
    }
    float* mout = msg + (size_t)n * (SH_DIM * C_DIM) + (size_t)(l * l) * C_DIM + c0;
    #pragma unroll
    for (int m = 0; m < 7; ++m)
        if (m < nm) *(float2*)(mout + (size_t)m * C_DIM) = make_float2(acc[m][0], acc[m][1]);
}

// ---------------- fallback fused gather (round-7, e-indexed) ----------------
__global__ __launch_bounds__(512, 4) void fused_gather_kernel(
    const int* __restrict__ perm, const int* __restrict__ offs,
    const int* __restrict__ sender, const float* __restrict__ x,
    const float* __restrict__ edge_attrs, const float* __restrict__ h3,
    const float* __restrict__ w4, float* __restrict__ msg)
{
    int n = blockIdx.x, t = threadIdx.x;
    int c = t & 127, l = t >> 7;
    float wc[RAD_H];
    #pragma unroll
    for (int k = 0; k < RAD_H; ++k)
        wc[k] = w4[k * (NL * C_DIM) + l * C_DIM + c];

    float acc[7] = {0.f, 0.f, 0.f, 0.f, 0.f, 0.f, 0.f};
    int nm = 2 * l + 1;
    int start = offs[n], end = offs[n + 1];
    if (start < end) {
        int e = __builtin_amdgcn_readfirstlane(perm[start]);
        int s = __builtin_amdgcn_readfirstlane(sender[e]);
        for (int idx = start; idx < end; ++idx) {
            #pragma unroll
            for (int k = 0; k < RAD_H; k += 8)
                asm volatile("" : "+v"(wc[k]), "+v"(wc[k+1]), "+v"(wc[k+2]), "+v"(wc[k+3]),
                                  "+v"(wc[k+4]), "+v"(wc[k+5]), "+v"(wc[k+6]), "+v"(wc[k+7]));
            int e_cur = e, s_cur = s;
            if (idx + 1 < end) {
                e = __builtin_amdgcn_readfirstlane(perm[idx + 1]);
                s = __builtin_amdgcn_readfirstlane(sender[e]);
            }
            const float* h3r = h3 + (size_t)e_cur * RAD_H;
            float xv = x[(size_t)s_cur * C_DIM + c];
            float tp0 = 0.f, tp1 = 0.f, tp2 = 0.f, tp3 = 0.f;
            #pragma unroll
            for (int q = 0; q < RAD_H / 4; ++q) {
                tp0 += h3r[4 * q + 0] * wc[4 * q + 0];
                tp1 += h3r[4 * q + 1] * wc[4 * q + 1];
                tp2 += h3r[4 * q + 2] * wc[4 * q + 2];
                tp3 += h3r[4 * q + 3] * wc[4 * q + 3];
            }
            float tp = (tp0 + tp1) + (tp2 + tp3);
            float xt = xv * (tp * R_SCALE);
            const float* ear = edge_attrs + (size_t)e_cur * SH_DIM + l * l;
            #pragma unroll
            for (int j = 0; j < 7; ++j)
                if (j < nm) acc[j] += ear[j] * xt;
        }
    }
    float* mout = msg + (size_t)n * (SH_DIM * C_DIM) + (size_t)(l * l) * C_DIM + c;
    #pragma unroll
    for (int j = 0; j < 7; ++j)
        if (j < nm) mout[(size_t)j * C_DIM] = acc[j];
}

// ---------------- out transform via MFMA: per l, [M_l x 128] @ w_out[l] (in place on d_out) ----------------
__global__ __launch_bounds__(256, 2) void out_mfma_kernel(
    float* __restrict__ out, const float* __restrict__ w_out)
{
    __shared__ unsigned short As[64 * 136];
    __shared__ unsigned short Bp[128 * 136];
    int l = blockIdx.y, t = threadIdx.x;
    int lane = t & 63, wid = t >> 6;
    const int cnt = 2 * l + 1, ms = l * l;
    const int M = N_NODES * cnt;
    const int ntile = (M + 63) >> 6;
    if (blockIdx.x >= ntile) return;

    for (int idx = t; idx < C_DIM * C_DIM; idx += 256) {
        int k = idx >> 7, n = idx & 127;
        Bp[n * 136 + k] = bf16bits(w_out[((size_t)l * C_DIM + k) * C_DIM + n] * OUT_SCALE);
    }
    __syncthreads();

    for (int tile = blockIdx.x; tile < ntile; tile += gridDim.x) {
        int i0 = tile << 6;
        {
            int r = t >> 2, q = t & 3;
            int g = min(i0 + r, M - 1);
            int node = g / cnt, mm = ms + (g - node * cnt);
            const float4* src = (const float4*)(out + ((size_t)node * SH_DIM + mm) * C_DIM + q * 32);
            unsigned short tmp[32];
            #pragma unroll
            for (int v = 0; v < 8; ++v) {
                float4 fv = src[v];
                tmp[v * 4 + 0] = bf16bits(fv.x);
                tmp[v * 4 + 1] = bf16bits(fv.y);
                tmp[v * 4 + 2] = bf16bits(fv.z);
                tmp[v * 4 + 3] = bf16bits(fv.w);
            }
            #pragma unroll
            for (int v = 0; v < 4; ++v)
                *(short8*)&As[r * 136 + q * 32 + v * 8] = *(short8*)&tmp[v * 8];
        }
        __syncthreads();

        f32x4 acc[8] = {};
        #pragma unroll
        for (int ks = 0; ks < 4; ++ks) {
            short8 a = *(const short8*)&As[(wid * 16 + (lane & 15)) * 136 + ks * 32 + (lane >> 4) * 8];
            #pragma unroll
            for (int f = 0; f < 8; ++f) {
                short8 b = *(const short8*)&Bp[(f * 16 + (lane & 15)) * 136 + ks * 32 + (lane >> 4) * 8];
                acc[f] = __builtin_amdgcn_mfma_f32_16x16x32_bf16(a, b, acc[f], 0, 0, 0);
            }
        }
        __syncthreads();

        #pragma unroll
        for (int r = 0; r < 4; ++r) {
            int g = i0 + wid * 16 + (lane >> 4) * 4 + r;
            if (g < M) {
                int node = g / cnt, mm = ms + (g - node * cnt);
                float* dst = out + ((size_t)node * SH_DIM + mm) * C_DIM + (lane & 15);
                #pragma unroll
                for (int f = 0; f < 8; ++f)
                    dst[f * 16] = acc[f][r];
            }
        }
    }
}

extern "C" void kernel_launch(void* const* d_in, const int* in_sizes, int n_in,
                              void* d_out, int out_size, void* d_ws, size_t ws_size,
                              hipStream_t stream)
{
    const float* node_attrs = (const float*)d_in[0];
    const float* node_feats = (const float*)d_in[1];
    const float* edge_attrs = (const float*)d_in[2];
    const float* edge_feats = (const float*)d_in[3];
    const int*   edge_index = (const int*)d_in[4];
    const float* w_up   = (const float*)d_in[5];
    const float* w_rad1 = (const float*)d_in[6];
    const float* w_rad2 = (const float*)d_in[7];
    const float* w_rad3 = (const float*)d_in[8];
    const float* w_rad4 = (const float*)d_in[9];
    const float* w_skip = (const float*)d_in[10];
    const float* w_out  = (const float*)d_in[11];
    const int* sender = edge_index;
    const int* recv   = edge_index + N_EDGE;

    float* out = (float*)d_out;                                 // msg staged here, then in-place
    float* sc  = out + (size_t)N_NODES * SH_DIM * C_DIM;

    // workspace layout (ws >= 233.4 MB proven; this needs ~138 MB)
    float* x   = (float*)d_ws;
    float* h3  = x + (size_t)N_NODES * C_DIM;
    int* deg    = (int*)(h3 + (size_t)N_EDGE * RAD_H);
    int* cursor = deg + 5120;
    int* offs   = cursor + 5120;
    int* perm   = offs + 5124;
    __hip_bfloat16* tpw = (__hip_bfloat16*)(perm + N_EDGE);
    int* sid_arr = (int*)(tpw + (size_t)N_EDGE * NL * C_DIM);
    float* ea_perm = (float*)(sid_arr + N_EDGE);
    size_t need = (size_t)((char*)(ea_perm + (size_t)N_EDGE * SH_DIM) - (char*)d_ws);
    int mode = (ws_size >= need) ? 1 : 0;

    hipMemsetAsync(deg, 0, 2 * 5120 * sizeof(int), stream);

    node_kernel<<<N_NODES, 128, 0, stream>>>(node_attrs, node_feats, w_skip, w_up, x, sc);
    radial_mfma_kernel<<<391, 256, 0, stream>>>(edge_feats, w_rad1, w_rad2, w_rad3, h3);

    hist_kernel<<<(N_EDGE + 255) / 256, 256, 0, stream>>>(recv, deg);
    scan_kernel<<<1, 256, 0, stream>>>(deg, offs);
    scatter_kernel<<<(N_EDGE + 255) / 256, 256, 0, stream>>>(recv, offs, cursor, perm);

    if (mode == 1) {
        reorder_kernel<<<(N_EDGE + 255) / 256, 256, 0, stream>>>(perm, sender, edge_attrs, sid_arr, (float4*)ea_perm);
        tpw_gemm_kernel<<<dim3(391, 4), 256, 0, stream>>>(perm, h3, w_rad4, tpw);
        stream_gather_kernel<<<N_NODES, 256, 0, stream>>>(offs, sid_arr, x, ea_perm, tpw, out);
    } else {
        fused_gather_kernel<<<N_NODES, 512, 0, stream>>>(perm, offs, sender, x, edge_attrs, h3, w_rad4, out);
    }

    out_mfma_kernel<<<dim3(547, 4), 256, 0, stream>>>(out, w_out);
}

// Round 23
// 202.669 us; speedup vs baseline: 1.8093x; 1.1899x over previous
//
#include <hip/hip_runtime.h>
#include <hip/hip_bf16.h>
#include <math.h>

#define N_NODES 5000
#define N_ELEMS 10
#define C_DIM   128
#define N_EDGE  100000
#define N_BES   8
#define RAD_H   64
#define NL      4
#define SH_DIM  16
#define TPW_ROWS 64

// scales
#define SC_SCALE 0.02795084971874737f    // 1/sqrt(128*10)
#define X_SCALE  0.08838834764831845f    // 1/sqrt(128)
#define R1_SCALE 0.3535533905932738f     // 1/sqrt(8)
#define R_SCALE  0.125f                  // 1/sqrt(64)
#define OUT_SCALE 0.004419417382415922f  // (1/sqrt(128))/20

typedef __attribute__((ext_vector_type(8))) short short8;
typedef __attribute__((ext_vector_type(4))) float f32x4;

__device__ __forceinline__ float silu(float v) { return v / (1.f + __expf(-v)); }
__device__ __forceinline__ unsigned short bf16bits(float v) {
    __hip_bfloat16 h = __float2bfloat16(v);
    return *(unsigned short*)&h;
}

// ---------------- node kernel: sc + x ----------------
__global__ __launch_bounds__(128) void node_kernel(
    const float* __restrict__ node_attrs, const float* __restrict__ node_feats,
    const float* __restrict__ w_skip, const float* __restrict__ w_up,
    float* __restrict__ x, float* __restrict__ sc_out)
{
    int n = blockIdx.x, t = threadIdx.x;
    __shared__ float f[C_DIM];
    __shared__ float at[N_ELEMS];
    f[t] = node_feats[(size_t)n * C_DIM + t];
    if (t < N_ELEMS) at[t] = node_attrs[(size_t)n * N_ELEMS + t];
    __syncthreads();

    float acc = 0.f;
    for (int a = 0; a < N_ELEMS; ++a) {
        float av = at[a];
        if (av != 0.f) {
            const float* wp = w_skip + a * C_DIM + t;
            float s2 = 0.f;
            #pragma unroll 8
            for (int c = 0; c < C_DIM; ++c) s2 += f[c] * wp[(size_t)c * (N_ELEMS * C_DIM)];
            acc += av * s2;
        }
    }
    sc_out[(size_t)n * C_DIM + t] = acc * SC_SCALE;

    float xa = 0.f;
    #pragma unroll 8
    for (int k = 0; k < C_DIM; ++k) xa += f[k] * w_up[k * C_DIM + t];
    x[(size_t)n * C_DIM + t] = xa * X_SCALE;
}

// ---------------- radial MLP v3: MFMA for layers 2+3 ----------------
__global__ __launch_bounds__(256, 2) void radial_mfma_kernel(
    const float* __restrict__ edge_feats,
    const float* __restrict__ w1, const float* __restrict__ w2, const float* __restrict__ w3,
    float* __restrict__ h3out)
{
    __shared__ unsigned short As[64 * 72];
    __shared__ unsigned short w2t[64 * 72];
    __shared__ unsigned short w3t[64 * 72];
    int t = threadIdx.x;
    int lane = t & 63, wid = t >> 6;

    for (int idx = t; idx < RAD_H * RAD_H; idx += 256) {
        int k = idx >> 6, n = idx & 63;
        w2t[n * 72 + k] = bf16bits(w2[k * RAD_H + n] * R_SCALE);
        w3t[n * 72 + k] = bf16bits(w3[k * RAD_H + n] * R_SCALE);
    }
    __syncthreads();

    short8 b2[2][4], b3[2][4];
    #pragma unroll
    for (int s = 0; s < 2; ++s)
        #pragma unroll
        for (int f = 0; f < 4; ++f) {
            b2[s][f] = *(const short8*)&w2t[(f * 16 + (lane & 15)) * 72 + s * 32 + (lane >> 4) * 8];
            b3[s][f] = *(const short8*)&w3t[(f * 16 + (lane & 15)) * 72 + s * 32 + (lane >> 4) * 8];
        }

    float w1r[N_BES];
    #pragma unroll
    for (int k = 0; k < N_BES; ++k) w1r[k] = w1[k * RAD_H + lane] * R1_SCALE;

    const int ntiles = (N_EDGE + 63) >> 6;
    for (int tile = blockIdx.x; tile < ntiles; tile += gridDim.x) {
        int i0 = tile << 6;
        int ebase = __builtin_amdgcn_readfirstlane(i0 + wid * 16);

        #pragma unroll 4
        for (int ee = 0; ee < 16; ++ee) {
            int e = min(ebase + ee, N_EDGE - 1);
            const float* ef = edge_feats + (size_t)e * N_BES;
            float a = 0.f;
            #pragma unroll
            for (int k = 0; k < N_BES; ++k) a += ef[k] * w1r[k];
            As[(wid * 16 + ee) * 72 + lane] = bf16bits(silu(a));
        }
        __builtin_amdgcn_wave_barrier();

        {
            short8 a0 = *(const short8*)&As[(wid * 16 + (lane & 15)) * 72 + 0 * 32 + (lane >> 4) * 8];
            short8 a1 = *(const short8*)&As[(wid * 16 + (lane & 15)) * 72 + 1 * 32 + (lane >> 4) * 8];
            f32x4 acc[4] = {};
            #pragma unroll
            for (int f = 0; f < 4; ++f) {
                acc[f] = __builtin_amdgcn_mfma_f32_16x16x32_bf16(a0, b2[0][f], acc[f], 0, 0, 0);
                acc[f] = __builtin_amdgcn_mfma_f32_16x16x32_bf16(a1, b2[1][f], acc[f], 0, 0, 0);
            }
            __builtin_amdgcn_wave_barrier();
            #pragma unroll
            for (int f = 0; f < 4; ++f)
                #pragma unroll
                for (int r = 0; r < 4; ++r)
                    As[(wid * 16 + (lane >> 4) * 4 + r) * 72 + f * 16 + (lane & 15)] =
                        bf16bits(silu(acc[f][r]));
        }
        __builtin_amdgcn_wave_barrier();

        {
            short8 a0 = *(const short8*)&As[(wid * 16 + (lane & 15)) * 72 + 0 * 32 + (lane >> 4) * 8];
            short8 a1 = *(const short8*)&As[(wid * 16 + (lane & 15)) * 72 + 1 * 32 + (lane >> 4) * 8];
            f32x4 acc[4] = {};
            #pragma unroll
            for (int f = 0; f < 4; ++f) {
                acc[f] = __builtin_amdgcn_mfma_f32_16x16x32_bf16(a0, b3[0][f], acc[f], 0, 0, 0);
                acc[f] = __builtin_amdgcn_mfma_f32_16x16x32_bf16(a1, b3[1][f], acc[f], 0, 0, 0);
            }
            #pragma unroll
            for (int r = 0; r < 4; ++r) {
                int e = i0 + wid * 16 + (lane >> 4) * 4 + r;
                if (e < N_EDGE) {
                    float* dst = h3out + (size_t)e * RAD_H + (lane & 15);
                    #pragma unroll
                    for (int f = 0; f < 4; ++f)
                        dst[f * 16] = silu(acc[f][r]);
                }
            }
        }
        __builtin_amdgcn_wave_barrier();
    }
}

// ---------------- CSR build ----------------
__global__ void hist_kernel(const int* __restrict__ recv, int* __restrict__ deg)
{
    int e = blockIdx.x * 256 + threadIdx.x;
    if (e < N_EDGE) atomicAdd(&deg[recv[e]], 1);
}

__global__ __launch_bounds__(256) void scan_kernel(const int* __restrict__ deg, int* __restrict__ offs)
{
    __shared__ int sums[256];
    int t = threadIdx.x;
    int base = t * 20;
    int loc[20]; int s = 0;
    #pragma unroll
    for (int i = 0; i < 20; ++i) { int idx = base + i; int v = (idx < N_NODES) ? deg[idx] : 0; loc[i] = s; s += v; }
    sums[t] = s; __syncthreads();
    for (int off = 1; off < 256; off <<= 1) {
        int v = (t >= off) ? sums[t - off] : 0;
        __syncthreads();
        sums[t] += v;
        __syncthreads();
    }
    int ex = (t == 0) ? 0 : sums[t - 1];
    #pragma unroll
    for (int i = 0; i < 20; ++i) { int idx = base + i; if (idx < N_NODES) offs[idx] = ex + loc[i]; }
    if (t == 255) offs[N_NODES] = sums[255];
}

__global__ void scatter_kernel(const int* __restrict__ recv, const int* __restrict__ offs,
                               int* __restrict__ cursor, int* __restrict__ perm)
{
    int e = blockIdx.x * 256 + threadIdx.x;
    if (e < N_EDGE) {
        int r = recv[e];
        int pos = atomicAdd(&cursor[r], 1);
        perm[offs[r] + pos] = e;
    }
}

// ---------------- reorder: sid_arr[idx]=sender[perm[idx]], ea_perm[idx]=edge_attrs[perm[idx]] ----------------
__global__ void reorder_kernel(const int* __restrict__ perm, const int* __restrict__ sender,
                               const float* __restrict__ edge_attrs,
                               int* __restrict__ sid_arr, float4* __restrict__ ea_perm4)
{
    int idx = blockIdx.x * 256 + threadIdx.x;
    if (idx < N_EDGE) {
        int e = perm[idx];
        sid_arr[idx] = sender[e];
        const float4* src = (const float4*)(edge_attrs + (size_t)e * SH_DIM);
        float4* dst = ea_perm4 + (size_t)idx * 4;
        dst[0] = src[0]; dst[1] = src[1]; dst[2] = src[2]; dst[3] = src[3];
    }
}

// ---------------- tpw GEMM via MFMA (bf16): tpw[i,:] = h3[perm[i],:] @ w4*R_SCALE ----------------
__global__ __launch_bounds__(256, 2) void tpw_gemm_kernel(
    const int* __restrict__ perm, const float* __restrict__ h3,
    const float* __restrict__ w4, __hip_bfloat16* __restrict__ tpw)
{
    __shared__ unsigned short As[64 * 72];
    __shared__ unsigned short Bp[128 * 72];
    __shared__ unsigned short epi[64 * 136];
    int l = blockIdx.y, t = threadIdx.x;
    int lane = t & 63, wid = t >> 6;

    for (int idx = t; idx < RAD_H * C_DIM; idx += 256) {
        int k = idx >> 7, n = idx & 127;
        Bp[n * 72 + k] = bf16bits(w4[k * (NL * C_DIM) + l * C_DIM + n] * R_SCALE);
    }
    __syncthreads();

    short8 bfr[2][8];
    #pragma unroll
    for (int s = 0; s < 2; ++s)
        #pragma unroll
        for (int f = 0; f < 8; ++f)
            bfr[s][f] = *(const short8*)&Bp[(f * 16 + (lane & 15)) * 72 + s * 32 + (lane >> 4) * 8];

    const int ntiles = (N_EDGE + TPW_ROWS - 1) / TPW_ROWS;
    for (int tile = blockIdx.x; tile < ntiles; tile += gridDim.x) {
        int i0 = tile * TPW_ROWS;
        {
            int r = t >> 2, q = t & 3;
            int e = perm[min(i0 + r, N_EDGE - 1)];
            const float4* src = (const float4*)(h3 + (size_t)e * RAD_H + q * 16);
            unsigned short tmp[16];
            #pragma unroll
            for (int v = 0; v < 4; ++v) {
                float4 fv = src[v];
                tmp[v * 4 + 0] = bf16bits(fv.x);
                tmp[v * 4 + 1] = bf16bits(fv.y);
                tmp[v * 4 + 2] = bf16bits(fv.z);
                tmp[v * 4 + 3] = bf16bits(fv.w);
            }
            *(short8*)&As[r * 72 + q * 16]     = *(short8*)&tmp[0];
            *(short8*)&As[r * 72 + q * 16 + 8] = *(short8*)&tmp[8];
        }
        __syncthreads();

        f32x4 acc[8] = {};
        #pragma unroll
        for (int s = 0; s < 2; ++s) {
            short8 a = *(const short8*)&As[(wid * 16 + (lane & 15)) * 72 + s * 32 + (lane >> 4) * 8];
            #pragma unroll
            for (int f = 0; f < 8; ++f)
                acc[f] = __builtin_amdgcn_mfma_f32_16x16x32_bf16(a, bfr[s][f], acc[f], 0, 0, 0);
        }
        #pragma unroll
        for (int f = 0; f < 8; ++f)
            #pragma unroll
            for (int r = 0; r < 4; ++r)
                epi[(wid * 16 + (lane >> 4) * 4 + r) * 136 + f * 16 + (lane & 15)] = bf16bits(acc[f][r]);
        __syncthreads();

        {
            int row = t >> 2, q = t & 3;
            if (i0 + row < N_EDGE) {
                unsigned short* dst = (unsigned short*)tpw + (size_t)(i0 + row) * (NL * C_DIM) + l * C_DIM + q * 32;
                #pragma unroll
                for (int v = 0; v < 4; ++v)
                    *(short8*)(dst + v * 8) = *(const short8*)&epi[row * 136 + q * 32 + v * 8];
            }
        }
    }
}

// ---------------- stream gather v5: ea+sid staged to LDS (kill scalar-cache streaming) ----------------
// Round-22 lesson: batch-8 went in flight (VGPR 32) but perf unchanged ->
// vmem MLP isn't the binder. Remaining streamed path: sid/ea via s_loads
// (25.6 MB of scalar-cache traffic). Both arrays are CONTIGUOUS in idx ->
// stage per-block span with coalesced float4 vector loads into LDS.
__global__ __launch_bounds__(256, 4) void stream_gather_kernel(
    const int* __restrict__ offs, const int* __restrict__ sid_arr,
    const float* __restrict__ x, const float* __restrict__ ea_perm,
    const __hip_bfloat16* __restrict__ tpw, float* __restrict__ msg)
{
    __shared__ float eas[128 * SH_DIM];   // 8 KB
    __shared__ int   sids[128];
    int n = blockIdx.x, t = threadIdx.x;
    int cq = t & 63, l = t >> 6;          // l wave-uniform; c = cq*2, cq*2+1
    int c0 = cq * 2;
    float acc[7][2] = {};
    int nm = 2 * l + 1;
    int start = offs[n], end = offs[n + 1];

    for (int cs = start; cs < end; cs += 128) {
        int clen = min(128, end - cs);
        {   // coalesced staging (contiguous in idx)
            const float4* src = (const float4*)(ea_perm + (size_t)cs * SH_DIM);
            float4* dst = (float4*)eas;
            for (int i = t; i < clen * 4; i += 256) dst[i] = src[i];
            for (int i = t; i < clen; i += 256) sids[i] = sid_arr[cs + i];
        }
        __syncthreads();

        for (int base = 0; base < clen; base += 8) {
            int idxb[8], sidb[8];
            #pragma unroll
            for (int j = 0; j < 8; ++j) idxb[j] = min(base + j, clen - 1);
            #pragma unroll
            for (int j = 0; j < 8; ++j) sidb[j] = sids[idxb[j]];        // LDS broadcast

            unsigned int tpb[8];
            float2 xv[8];
            #pragma unroll
            for (int j = 0; j < 8; ++j)
                tpb[j] = *(const unsigned int*)((const unsigned short*)tpw
                          + (size_t)(cs + idxb[j]) * (NL * C_DIM) + l * C_DIM + c0);
            #pragma unroll
            for (int j = 0; j < 8; ++j)
                xv[j] = *(const float2*)(x + (size_t)sidb[j] * C_DIM + c0);
            asm volatile("" : "+v"(tpb[0]), "+v"(tpb[1]), "+v"(tpb[2]), "+v"(tpb[3]),
                              "+v"(tpb[4]), "+v"(tpb[5]), "+v"(tpb[6]), "+v"(tpb[7]),
                              "+v"(xv[0].x), "+v"(xv[0].y), "+v"(xv[1].x), "+v"(xv[1].y),
                              "+v"(xv[2].x), "+v"(xv[2].y), "+v"(xv[3].x), "+v"(xv[3].y),
                              "+v"(xv[4].x), "+v"(xv[4].y), "+v"(xv[5].x), "+v"(xv[5].y),
                              "+v"(xv[6].x), "+v"(xv[6].y), "+v"(xv[7].x), "+v"(xv[7].y));

            #pragma unroll
            for (int j = 0; j < 8; ++j) {
                unsigned int lo = (tpb[j] & 0xFFFFu) << 16;
                unsigned int hi = tpb[j] & 0xFFFF0000u;
                float tp0 = __uint_as_float(lo);
                float tp1 = __uint_as_float(hi);
                bool valid = (base + j < clen);
                float xt0 = valid ? tp0 * xv[j].x : 0.f;
                float xt1 = valid ? tp1 * xv[j].y : 0.f;
                const float* ear = eas + idxb[j] * SH_DIM + l * l;      // LDS broadcast
                #pragma unroll
                for (int m = 0; m < 7; ++m)
                    if (m < nm) { acc[m][0] += ear[m] * xt0; acc[m][1] += ear[m] * xt1; }
            }
        }
        __syncthreads();   // before re-staging next chunk
    }
    float* mout = msg + (size_t)n * (SH_DIM * C_DIM) + (size_t)(l * l) * C_DIM + c0;
    #pragma unroll
    for (int m = 0; m < 7; ++m)
        if (m < nm) *(float2*)(mout + (size_t)m * C_DIM) = make_float2(acc[m][0], acc[m][1]);
}

// ---------------- fallback fused gather (round-7, e-indexed) ----------------
__global__ __launch_bounds__(512, 4) void fused_gather_kernel(
    const int* __restrict__ perm, const int* __restrict__ offs,
    const int* __restrict__ sender, const float* __restrict__ x,
    const float* __restrict__ edge_attrs, const float* __restrict__ h3,
    const float* __restrict__ w4, float* __restrict__ msg)
{
    int n = blockIdx.x, t = threadIdx.x;
    int c = t & 127, l = t >> 7;
    float wc[RAD_H];
    #pragma unroll
    for (int k = 0; k < RAD_H; ++k)
        wc[k] = w4[k * (NL * C_DIM) + l * C_DIM + c];

    float acc[7] = {0.f, 0.f, 0.f, 0.f, 0.f, 0.f, 0.f};
    int nm = 2 * l + 1;
    int start = offs[n], end = offs[n + 1];
    if (start < end) {
        int e = __builtin_amdgcn_readfirstlane(perm[start]);
        int s = __builtin_amdgcn_readfirstlane(sender[e]);
        for (int idx = start; idx < end; ++idx) {
            #pragma unroll
            for (int k = 0; k < RAD_H; k += 8)
                asm volatile("" : "+v"(wc[k]), "+v"(wc[k+1]), "+v"(wc[k+2]), "+v"(wc[k+3]),
                                  "+v"(wc[k+4]), "+v"(wc[k+5]), "+v"(wc[k+6]), "+v"(wc[k+7]));
            int e_cur = e, s_cur = s;
            if (idx + 1 < end) {
                e = __builtin_amdgcn_readfirstlane(perm[idx + 1]);
                s = __builtin_amdgcn_readfirstlane(sender[e]);
            }
            const float* h3r = h3 + (size_t)e_cur * RAD_H;
            float xv = x[(size_t)s_cur * C_DIM + c];
            float tp0 = 0.f, tp1 = 0.f, tp2 = 0.f, tp3 = 0.f;
            #pragma unroll
            for (int q = 0; q < RAD_H / 4; ++q) {
                tp0 += h3r[4 * q + 0] * wc[4 * q + 0];
                tp1 += h3r[4 * q + 1] * wc[4 * q + 1];
                tp2 += h3r[4 * q + 2] * wc[4 * q + 2];
                tp3 += h3r[4 * q + 3] * wc[4 * q + 3];
            }
            float tp = (tp0 + tp1) + (tp2 + tp3);
            float xt = xv * (tp * R_SCALE);
            const float* ear = edge_attrs + (size_t)e_cur * SH_DIM + l * l;
            #pragma unroll
            for (int j = 0; j < 7; ++j)
                if (j < nm) acc[j] += ear[j] * xt;
        }
    }
    float* mout = msg + (size_t)n * (SH_DIM * C_DIM) + (size_t)(l * l) * C_DIM + c;
    #pragma unroll
    for (int j = 0; j < 7; ++j)
        if (j < nm) mout[(size_t)j * C_DIM] = acc[j];
}

// ---------------- out transform via MFMA: per l, [M_l x 128] @ w_out[l] (in place on d_out) ----------------
__global__ __launch_bounds__(256, 2) void out_mfma_kernel(
    float* __restrict__ out, const float* __restrict__ w_out)
{
    __shared__ unsigned short As[64 * 136];
    __shared__ unsigned short Bp[128 * 136];
    int l = blockIdx.y, t = threadIdx.x;
    int lane = t & 63, wid = t >> 6;
    const int cnt = 2 * l + 1, ms = l * l;
    const int M = N_NODES * cnt;
    const int ntile = (M + 63) >> 6;
    if (blockIdx.x >= ntile) return;

    for (int idx = t; idx < C_DIM * C_DIM; idx += 256) {
        int k = idx >> 7, n = idx & 127;
        Bp[n * 136 + k] = bf16bits(w_out[((size_t)l * C_DIM + k) * C_DIM + n] * OUT_SCALE);
    }
    __syncthreads();

    for (int tile = blockIdx.x; tile < ntile; tile += gridDim.x) {
        int i0 = tile << 6;
        {
            int r = t >> 2, q = t & 3;
            int g = min(i0 + r, M - 1);
            int node = g / cnt, mm = ms + (g - node * cnt);
            const float4* src = (const float4*)(out + ((size_t)node * SH_DIM + mm) * C_DIM + q * 32);
            unsigned short tmp[32];
            #pragma unroll
            for (int v = 0; v < 8; ++v) {
                float4 fv = src[v];
                tmp[v * 4 + 0] = bf16bits(fv.x);
                tmp[v * 4 + 1] = bf16bits(fv.y);
                tmp[v * 4 + 2] = bf16bits(fv.z);
                tmp[v * 4 + 3] = bf16bits(fv.w);
            }
            #pragma unroll
            for (int v = 0; v < 4; ++v)
                *(short8*)&As[r * 136 + q * 32 + v * 8] = *(short8*)&tmp[v * 8];
        }
        __syncthreads();

        f32x4 acc[8] = {};
        #pragma unroll
        for (int ks = 0; ks < 4; ++ks) {
            short8 a = *(const short8*)&As[(wid * 16 + (lane & 15)) * 136 + ks * 32 + (lane >> 4) * 8];
            #pragma unroll
            for (int f = 0; f < 8; ++f) {
                short8 b = *(const short8*)&Bp[(f * 16 + (lane & 15)) * 136 + ks * 32 + (lane >> 4) * 8];
                acc[f] = __builtin_amdgcn_mfma_f32_16x16x32_bf16(a, b, acc[f], 0, 0, 0);
            }
        }
        __syncthreads();

        #pragma unroll
        for (int r = 0; r < 4; ++r) {
            int g = i0 + wid * 16 + (lane >> 4) * 4 + r;
            if (g < M) {
                int node = g / cnt, mm = ms + (g - node * cnt);
                float* dst = out + ((size_t)node * SH_DIM + mm) * C_DIM + (lane & 15);
                #pragma unroll
                for (int f = 0; f < 8; ++f)
                    dst[f * 16] = acc[f][r];
            }
        }
    }
}

extern "C" void kernel_launch(void* const* d_in, const int* in_sizes, int n_in,
                              void* d_out, int out_size, void* d_ws, size_t ws_size,
                              hipStream_t stream)
{
    const float* node_attrs = (const float*)d_in[0];
    const float* node_feats = (const float*)d_in[1];
    const float* edge_attrs = (const float*)d_in[2];
    const float* edge_feats = (const float*)d_in[3];
    const int*   edge_index = (const int*)d_in[4];
    const float* w_up   = (const float*)d_in[5];
    const float* w_rad1 = (const float*)d_in[6];
    const float* w_rad2 = (const float*)d_in[7];
    const float* w_rad3 = (const float*)d_in[8];
    const float* w_rad4 = (const float*)d_in[9];
    const float* w_skip = (const float*)d_in[10];
    const float* w_out  = (const float*)d_in[11];
    const int* sender = edge_index;
    const int* recv   = edge_index + N_EDGE;

    float* out = (float*)d_out;                                 // msg staged here, then in-place
    float* sc  = out + (size_t)N_NODES * SH_DIM * C_DIM;

    // workspace layout (ws >= 233.4 MB proven; this needs ~138 MB)
    float* x   = (float*)d_ws;
    float* h3  = x + (size_t)N_NODES * C_DIM;
    int* deg    = (int*)(h3 + (size_t)N_EDGE * RAD_H);
    int* cursor = deg + 5120;
    int* offs   = cursor + 5120;
    int* perm   = offs + 5124;
    __hip_bfloat16* tpw = (__hip_bfloat16*)(perm + N_EDGE);
    int* sid_arr = (int*)(tpw + (size_t)N_EDGE * NL * C_DIM);
    float* ea_perm = (float*)(sid_arr + N_EDGE);
    size_t need = (size_t)((char*)(ea_perm + (size_t)N_EDGE * SH_DIM) - (char*)d_ws);
    int mode = (ws_size >= need) ? 1 : 0;

    hipMemsetAsync(deg, 0, 2 * 5120 * sizeof(int), stream);

    node_kernel<<<N_NODES, 128, 0, stream>>>(node_attrs, node_feats, w_skip, w_up, x, sc);
    radial_mfma_kernel<<<391, 256, 0, stream>>>(edge_feats, w_rad1, w_rad2, w_rad3, h3);

    hist_kernel<<<(N_EDGE + 255) / 256, 256, 0, stream>>>(recv, deg);
    scan_kernel<<<1, 256, 0, stream>>>(deg, offs);
    scatter_kernel<<<(N_EDGE + 255) / 256, 256, 0, stream>>>(recv, offs, cursor, perm);

    if (mode == 1) {
        reorder_kernel<<<(N_EDGE + 255) / 256, 256, 0, stream>>>(perm, sender, edge_attrs, sid_arr, (float4*)ea_perm);
        tpw_gemm_kernel<<<dim3(391, 4), 256, 0, stream>>>(perm, h3, w_rad4, tpw);
        stream_gather_kernel<<<N_NODES, 256, 0, stream>>>(offs, sid_arr, x, ea_perm, tpw, out);
    } else {
        fused_gather_kernel<<<N_NODES, 512, 0, stream>>>(perm, offs, sender, x, edge_attrs, h3, w_rad4, out);
    }

    out_mfma_kernel<<<dim3(547, 4), 256, 0, stream>>>(out, w_out);
}